// Round 1
// 452.775 us; speedup vs baseline: 1.0110x; 1.0110x over previous
//
#include <hip/hip_runtime.h>
#include <hip/hip_bf16.h>
#include <math.h>

typedef __hip_bfloat16 bf16;
typedef unsigned short u16;
typedef __attribute__((ext_vector_type(8))) short short8;
typedef __attribute__((ext_vector_type(4))) float f32x4;

#define NB      8
#define SEQ     1024
#define EDIM    512
#define E2DIM   1024
#define ROWS    8192
#define INV_SQRT_E 0.04419417382415922f
#define ATT_SCL    0.06375985678148161f   /* INV_SQRT_E * log2(e) */

__device__ inline u16 f2bu(float f) {           // fp32 -> bf16 bits, RNE
    union { float f; unsigned u; } c; c.f = f;
    return (u16)((c.u + 0x7FFF + ((c.u >> 16) & 1)) >> 16);
}

// ---------------------------------------------------------------------------
// Input dtype autodetect (proved inputs are fp32; kept as cheap insurance).
// ---------------------------------------------------------------------------
__global__ __launch_bounds__(256) void detect_dtype(const u16* __restrict__ x,
                                                    int* __restrict__ flag) {
    int t = threadIdx.x;
    int cnt = 0;
    for (int k = t; k < 8192; k += 256) {
        int e = (x[k] >> 7) & 0xFF;
        if (e >= 0xC0) cnt++;
    }
#pragma unroll
    for (int o = 32; o > 0; o >>= 1) cnt += __shfl_xor(cnt, o);
    __shared__ int red[4];
    if ((t & 63) == 0) red[t >> 6] = cnt;
    __syncthreads();
    if (t == 0) flag[0] = (red[0] + red[1] + red[2] + red[3] > 100) ? 1 : 0;
}

// ---------------------------------------------------------------------------
// Batch conversion of all 23 inputs -> fp32 workspace (dtype-adaptive).
// ---------------------------------------------------------------------------
struct CvtBatch {
    const void* src[23];
    float4*     dst[23];
    int         pre4[24];
};

__global__ __launch_bounds__(256) void cvt_all(CvtBatch a, int total4,
                                               const int* __restrict__ flag) {
    int t = blockIdx.x * 256 + threadIdx.x;
    if (t >= total4) return;
    int lo = 0;
    while (t >= a.pre4[lo + 1]) lo++;
    int li = t - a.pre4[lo];
    if (flag[0]) {
        a.dst[lo][li] = ((const float4*)a.src[lo])[li];
    } else {
        ushort4 u = ((const ushort4*)a.src[lo])[li];
        union { unsigned int i; float f; } c;
        float4 o;
        c.i = ((unsigned)u.x) << 16; o.x = c.f;
        c.i = ((unsigned)u.y) << 16; o.y = c.f;
        c.i = ((unsigned)u.z) << 16; o.z = c.f;
        c.i = ((unsigned)u.w) << 16; o.w = c.f;
        a.dst[lo][li] = o;
    }
}

// fp32 -> bf16 elementwise, n/4 threads
__global__ __launch_bounds__(256) void f2b_kernel(const float* __restrict__ src,
                                                  u16* __restrict__ dst, int n4) {
    int i = blockIdx.x * 256 + threadIdx.x;
    if (i >= n4) return;
    float4 a = ((const float4*)src)[i];
    ushort4 o;
    o.x = f2bu(a.x); o.y = f2bu(a.y); o.z = f2bu(a.z); o.w = f2bu(a.w);
    ((ushort4*)dst)[i] = o;
}

// ---------------------------------------------------------------------------
// async global->LDS staging of a 128x32 bf16 tile (linear LDS, width=16).
// LDS dest is wave-uniform base + lane*16 (HW rule); global src is per-lane.
// ---------------------------------------------------------------------------
#define LDK 32   /* linear LDS row: 32 bf16 = 64 B (required by global_load_lds) */

__device__ __forceinline__ void stage128x32(const u16* g, int ld, u16* lds, int tid) {
    const int w = tid >> 6;              // wave id (uniform within wave)
    const int l = tid & 63;
    const int r = w * 16 + (l >> 2);     // row covered by this lane
    const int c = (l & 3) * 8;           // 16B chunk within row
    const u16* g0 = g + (size_t)r * ld + c;
    u16* l0 = lds + w * 16 * LDK;        // wave-uniform LDS base
    __builtin_amdgcn_global_load_lds(
        (const __attribute__((address_space(1))) void*)g0,
        (__attribute__((address_space(3))) void*)l0, 16, 0, 0);
    const u16* g1 = g0 + (size_t)64 * ld;
    u16* l1 = l0 + 64 * LDK;
    __builtin_amdgcn_global_load_lds(
        (const __attribute__((address_space(1))) void*)g1,
        (__attribute__((address_space(3))) void*)l1, 16, 0, 0);
}

// ---------------------------------------------------------------------------
// Fold batch: 6 spectral layers, z-indexed kernels (3 launches total).
// Mt[s][o][j] = sc * sum_m fw[m][o] * w[(m-j) mod n]
// ---------------------------------------------------------------------------
struct FoldBatch {
    const float* w[6];
    const float* fw[6];
    u16* t1[6];    // fwT bf16: t1[o][m] = bf16(fw[m][o])
    u16* t2[6];    // circ bf16: t2[j][m] = bf16(w[(m-j) mod n])
    u16* mt[6];    // output Mt bf16 [n][n]
    int  n[6], lg[6];
    float sc[6];
};

__global__ __launch_bounds__(256) void fold_trconv(FoldBatch fb) {
    const int z = blockIdx.z;
    const int n = fb.n[z];
    const int bx = blockIdx.x * 32, by = blockIdx.y * 32;
    if (bx >= n || by >= n) return;
    __shared__ float t[32][33];
    const int tx = threadIdx.x & 31, ty = threadIdx.x >> 5;   // 32x8
    const float* src = fb.fw[z];
    u16* dst = fb.t1[z];
#pragma unroll
    for (int r = 0; r < 32; r += 8)
        t[ty + r][tx] = src[(size_t)(by + ty + r) * n + bx + tx];
    __syncthreads();
#pragma unroll
    for (int r = 0; r < 32; r += 8)
        dst[(size_t)(bx + ty + r) * n + by + tx] = f2bu(t[tx][ty + r]);
}

__global__ __launch_bounds__(256) void fold_circ(FoldBatch fb) {
    const int z = blockIdx.z;
    const int n = fb.n[z], lg = fb.lg[z];
    int idx = blockIdx.x * 256 + threadIdx.x;
    if (idx >= n * n) return;
    int mask = n - 1;
    int m = idx & mask;
    int j = idx >> lg;
    fb.t2[z][idx] = f2bu(fb.w[z][(m - j) & mask]);
}

__global__ __launch_bounds__(256) void fold_gemm(FoldBatch fb) {
    const int z = blockIdx.z;
    const int n = fb.n[z];
    const int bm = blockIdx.y * 128, bn = blockIdx.x * 128;
    if (bm >= n || bn >= n) return;
    const u16* A  = fb.t1[z];
    const u16* Bt = fb.t2[z];
    u16* Mt = fb.mt[z];
    const float scale = fb.sc[z];

    __shared__ u16 Asl[128 * LDK];
    __shared__ u16 Bsl[128 * LDK];
    const int tid = threadIdx.x;
    const int lane = tid & 63, wave = tid >> 6;
    const int wy = wave >> 1, wx = wave & 1;
    const int qd = lane >> 4, ln16 = lane & 15;

    f32x4 acc[4][4];
#pragma unroll
    for (int i = 0; i < 4; i++)
#pragma unroll
        for (int j = 0; j < 4; j++)
#pragma unroll
            for (int r = 0; r < 4; r++) acc[i][j][r] = 0.f;

    for (int k0 = 0; k0 < n; k0 += 32) {
        stage128x32(A  + (size_t)bm * n + k0, n, Asl, tid);
        stage128x32(Bt + (size_t)bn * n + k0, n, Bsl, tid);
        __syncthreads();
        short8 af[4], bf_[4];
#pragma unroll
        for (int i = 0; i < 4; i++) {
            af[i]  = *(const short8*)&Asl[(wy * 64 + i * 16 + ln16) * LDK + qd * 8];
            bf_[i] = *(const short8*)&Bsl[(wx * 64 + i * 16 + ln16) * LDK + qd * 8];
        }
#pragma unroll
        for (int i = 0; i < 4; i++)
#pragma unroll
            for (int j = 0; j < 4; j++)
                acc[i][j] = __builtin_amdgcn_mfma_f32_16x16x32_bf16(af[i], bf_[j], acc[i][j], 0, 0, 0);
        __syncthreads();
    }
#pragma unroll
    for (int i = 0; i < 4; i++)
#pragma unroll
        for (int j = 0; j < 4; j++) {
            const int col = bn + wx * 64 + j * 16 + ln16;
#pragma unroll
            for (int r = 0; r < 4; r++) {
                const int row = bm + wy * 64 + i * 16 + qd * 4 + r;
                Mt[(size_t)row * n + col] = f2bu(acc[i][j][r] * scale);
            }
        }
}

// ---------------------------------------------------------------------------
// bf16 MFMA GEMM (single B): C = act( A @ B + bias ). B pre-transposed.
// 128x128 tile, BK=32, 4 waves, global_load_lds staging. mode: 0 none, 1 gelu.
// Optional outputs: Cf fp32, Cb bf16(v), Cb2 bf16(aux - v).
// ---------------------------------------------------------------------------
__global__ __launch_bounds__(256) void gemm_bf(
    const u16* __restrict__ A, int lda,
    const u16* __restrict__ Bt, int ldb,
    const float* __restrict__ bias,
    float* __restrict__ Cf, int ldc,
    u16* __restrict__ Cb, int ldcb,
    u16* __restrict__ Cb2, int ldcb2,
    const float* __restrict__ aux, int ldaux,
    int K, int mode)
{
    __shared__ u16 Asl[128 * LDK];
    __shared__ u16 Bsl[128 * LDK];
    const int tid = threadIdx.x;
    const int bm = blockIdx.y * 128, bn = blockIdx.x * 128;
    const int lane = tid & 63, wave = tid >> 6;
    const int wy = wave >> 1, wx = wave & 1;
    const int qd = lane >> 4, ln16 = lane & 15;

    f32x4 acc[4][4];
#pragma unroll
    for (int i = 0; i < 4; i++)
#pragma unroll
        for (int j = 0; j < 4; j++)
#pragma unroll
            for (int r = 0; r < 4; r++) acc[i][j][r] = 0.f;

    for (int k0 = 0; k0 < K; k0 += 32) {
        stage128x32(A  + (size_t)bm * lda + k0, lda, Asl, tid);
        stage128x32(Bt + (size_t)bn * ldb + k0, ldb, Bsl, tid);
        __syncthreads();
        short8 af[4], bf_[4];
#pragma unroll
        for (int i = 0; i < 4; i++) {
            af[i]  = *(const short8*)&Asl[(wy * 64 + i * 16 + ln16) * LDK + qd * 8];
            bf_[i] = *(const short8*)&Bsl[(wx * 64 + i * 16 + ln16) * LDK + qd * 8];
        }
#pragma unroll
        for (int i = 0; i < 4; i++)
#pragma unroll
            for (int j = 0; j < 4; j++)
                acc[i][j] = __builtin_amdgcn_mfma_f32_16x16x32_bf16(af[i], bf_[j], acc[i][j], 0, 0, 0);
        __syncthreads();
    }

#pragma unroll
    for (int i = 0; i < 4; i++) {
#pragma unroll
        for (int j = 0; j < 4; j++) {
            const int col = bn + wx * 64 + j * 16 + ln16;
            const float b_ = bias ? bias[col] : 0.f;
#pragma unroll
            for (int r = 0; r < 4; r++) {
                const int row = bm + wy * 64 + i * 16 + qd * 4 + r;
                float v = acc[i][j][r] + b_;
                if (mode == 1) v = 0.5f * v * (1.0f + erff(v * 0.7071067811865476f));
                if (Cf)  Cf[(size_t)row * ldc + col] = v;
                if (Cb)  Cb[(size_t)row * ldcb + col] = f2bu(v);
                if (Cb2) Cb2[(size_t)row * ldcb2 + col] =
                             f2bu(aux[(size_t)row * ldaux + col] - v);
            }
        }
    }
}

// ---------------------------------------------------------------------------
// Dual-B fused gate GEMM: C = sigmoid(A@B1 + b1) * (A@B2 + b2), fp32 out.
// Same tile structure, A staged once, 32 MFMA/iter/wave, async staging.
// ---------------------------------------------------------------------------
__global__ __launch_bounds__(256) void gemm_bf2(
    const u16* __restrict__ A, int lda,
    const u16* __restrict__ B1t, const u16* __restrict__ B2t, int ldb,
    const float* __restrict__ bias1, const float* __restrict__ bias2,
    float* __restrict__ Cf, int ldc, int K)
{
    __shared__ u16 Asl[128 * LDK];
    __shared__ u16 B1sl[128 * LDK];
    __shared__ u16 B2sl[128 * LDK];
    const int tid = threadIdx.x;
    const int bm = blockIdx.y * 128, bn = blockIdx.x * 128;
    const int lane = tid & 63, wave = tid >> 6;
    const int wy = wave >> 1, wx = wave & 1;
    const int qd = lane >> 4, ln16 = lane & 15;

    f32x4 acc1[4][4], acc2[4][4];
#pragma unroll
    for (int i = 0; i < 4; i++)
#pragma unroll
        for (int j = 0; j < 4; j++)
#pragma unroll
            for (int r = 0; r < 4; r++) { acc1[i][j][r] = 0.f; acc2[i][j][r] = 0.f; }

    for (int k0 = 0; k0 < K; k0 += 32) {
        stage128x32(A   + (size_t)bm * lda + k0, lda, Asl,  tid);
        stage128x32(B1t + (size_t)bn * ldb + k0, ldb, B1sl, tid);
        stage128x32(B2t + (size_t)bn * ldb + k0, ldb, B2sl, tid);
        __syncthreads();
        short8 af[4], b1f[4], b2f[4];
#pragma unroll
        for (int i = 0; i < 4; i++) {
            af[i]  = *(const short8*)&Asl[(wy * 64 + i * 16 + ln16) * LDK + qd * 8];
            b1f[i] = *(const short8*)&B1sl[(wx * 64 + i * 16 + ln16) * LDK + qd * 8];
            b2f[i] = *(const short8*)&B2sl[(wx * 64 + i * 16 + ln16) * LDK + qd * 8];
        }
#pragma unroll
        for (int i = 0; i < 4; i++)
#pragma unroll
            for (int j = 0; j < 4; j++) {
                acc1[i][j] = __builtin_amdgcn_mfma_f32_16x16x32_bf16(af[i], b1f[j], acc1[i][j], 0, 0, 0);
                acc2[i][j] = __builtin_amdgcn_mfma_f32_16x16x32_bf16(af[i], b2f[j], acc2[i][j], 0, 0, 0);
            }
        __syncthreads();
    }

#pragma unroll
    for (int i = 0; i < 4; i++) {
#pragma unroll
        for (int j = 0; j < 4; j++) {
            const int col = bn + wx * 64 + j * 16 + ln16;
            const float b1_ = bias1[col], b2_ = bias2[col];
#pragma unroll
            for (int r = 0; r < 4; r++) {
                const int row = bm + wy * 64 + i * 16 + qd * 4 + r;
                const float g = 1.0f / (1.0f + expf(-(acc1[i][j][r] + b1_)));
                Cf[(size_t)row * ldc + col] = g * (acc2[i][j][r] + b2_);
            }
        }
    }
}

// ---------------------------------------------------------------------------
// LayerNorm over 512 features. in1b optional bf16 add. fp32 + optional bf16 out.
// ---------------------------------------------------------------------------
__global__ __launch_bounds__(256) void ln_kernel(
    const float* __restrict__ in0, int ld0,
    const u16* __restrict__ in1b, int ld1b,
    const float* __restrict__ g, const float* __restrict__ bta,
    float* __restrict__ outf, int ldo,
    u16* __restrict__ outb, int ldob)
{
    int row = blockIdx.x, tid = threadIdx.x;
    const float* p0 = in0 + (size_t)row * ld0;
    float v0 = p0[tid], v1 = p0[tid + 256];
    if (in1b) {
        const u16* p1 = in1b + (size_t)row * ld1b;
        union { unsigned u; float f; } c0, c1;
        c0.u = ((unsigned)p1[tid]) << 16;
        c1.u = ((unsigned)p1[tid + 256]) << 16;
        v0 += c0.f; v1 += c1.f;
    }
    float s = v0 + v1, sq = v0 * v0 + v1 * v1;
#pragma unroll
    for (int o = 32; o > 0; o >>= 1) {
        s  += __shfl_xor(s, o);
        sq += __shfl_xor(sq, o);
    }
    __shared__ float red[8];
    int wid = tid >> 6;
    if ((tid & 63) == 0) { red[wid] = s; red[4 + wid] = sq; }
    __syncthreads();
    s  = red[0] + red[1] + red[2] + red[3];
    sq = red[4] + red[5] + red[6] + red[7];
    float mean = s * (1.0f / 512.0f);
    float var  = sq * (1.0f / 512.0f) - mean * mean;
    float rstd = rsqrtf(var + 1e-5f);
    float o0 = (v0 - mean) * rstd * g[tid] + bta[tid];
    float o1 = (v1 - mean) * rstd * g[tid + 256] + bta[tid + 256];
    if (outf) {
        outf[(size_t)row * ldo + tid]       = o0;
        outf[(size_t)row * ldo + tid + 256] = o1;
    }
    if (outb) {
        outb[(size_t)row * ldob + tid]       = f2bu(o0);
        outb[(size_t)row * ldob + tid + 256] = f2bu(o1);
    }
}

// ---------------------------------------------------------------------------
// MFMA flash attention, q==k==v bf16, head_dim 64. exp2-domain softmax.
// Writes bf16 new_x into catb[:, 0:512] (ld 1024).
// ---------------------------------------------------------------------------
#define AP 72   /* LDS pitch in bf16 elems */

__global__ __launch_bounds__(256) void attn_mfma(const u16* __restrict__ qall,
                                                 u16* __restrict__ catb) {
    __shared__ u16 Ks[64 * AP];        // [key][d]
    __shared__ u16 KsT[64 * AP];       // [d][key]
    __shared__ u16 Pw[4][16 * AP];     // per-wave P [row][key]

    const int bid = blockIdx.x;
    const int lt = bid & 15, hh = (bid >> 4) & 7, bb = bid >> 7;
    const int q0 = lt * 64;
    const int tid = threadIdx.x;
    const int wave = tid >> 6, lane = tid & 63;
    const int quad = lane >> 4, ln16 = lane & 15;

    const u16* qh = qall + (size_t)bb * SEQ * EDIM + hh * 64;

    const u16* qrow = qh + (size_t)(q0 + wave * 16 + ln16) * EDIM + quad * 8;
    const short8 aq0 = *(const short8*)(qrow);
    const short8 aq1 = *(const short8*)(qrow + 32);

    f32x4 oacc[4];
    float m_run[4], l_run[4];
#pragma unroll
    for (int j = 0; j < 4; j++)
#pragma unroll
        for (int r = 0; r < 4; r++) oacc[j][r] = 0.f;
#pragma unroll
    for (int r = 0; r < 4; r++) { m_run[r] = -1e30f; l_run[r] = 0.f; }

    const int sr  = tid & 63;
    const int scq = (tid >> 6) * 16;

    for (int s0 = 0; s0 < SEQ; s0 += 64) {
        __syncthreads();
        {
            const u16* krow = qh + (size_t)(s0 + sr) * EDIM + scq;
            uint4 v0 = *(const uint4*)(krow);
            uint4 v1 = *(const uint4*)(krow + 8);
            *(uint4*)&Ks[sr * AP + scq]     = v0;
            *(uint4*)&Ks[sr * AP + scq + 8] = v1;
            const u16* h0 = (const u16*)&v0;
            const u16* h1 = (const u16*)&v1;
#pragma unroll
            for (int i = 0; i < 8; i++) KsT[(scq + i) * AP + sr]     = h0[i];
#pragma unroll
            for (int i = 0; i < 8; i++) KsT[(scq + 8 + i) * AP + sr] = h1[i];
        }
        __syncthreads();

        f32x4 S[4];
#pragma unroll
        for (int j = 0; j < 4; j++) {
            const int krw = (j * 16 + ln16) * AP + quad * 8;
            short8 b0 = *(const short8*)&Ks[krw];
            short8 b1 = *(const short8*)&Ks[krw + 32];
            f32x4 c = {0.f, 0.f, 0.f, 0.f};
            c = __builtin_amdgcn_mfma_f32_16x16x32_bf16(aq0, b0, c, 0, 0, 0);
            c = __builtin_amdgcn_mfma_f32_16x16x32_bf16(aq1, b1, c, 0, 0, 0);
            S[j] = c;
        }

#pragma unroll
        for (int r = 0; r < 4; r++) {
            float v0_ = S[0][r] * ATT_SCL;       // log2-domain scores
            float v1_ = S[1][r] * ATT_SCL;
            float v2_ = S[2][r] * ATT_SCL;
            float v3_ = S[3][r] * ATT_SCL;
            float mx = fmaxf(fmaxf(v0_, v1_), fmaxf(v2_, v3_));
            mx = fmaxf(mx, __shfl_xor(mx, 1));
            mx = fmaxf(mx, __shfl_xor(mx, 2));
            mx = fmaxf(mx, __shfl_xor(mx, 4));
            mx = fmaxf(mx, __shfl_xor(mx, 8));
            float mn = fmaxf(m_run[r], mx);
            float al = exp2f(m_run[r] - mn);
            m_run[r] = mn;
            float p0 = exp2f(v0_ - mn), p1 = exp2f(v1_ - mn);
            float p2 = exp2f(v2_ - mn), p3 = exp2f(v3_ - mn);
            float rs = p0 + p1 + p2 + p3;
            rs += __shfl_xor(rs, 1); rs += __shfl_xor(rs, 2);
            rs += __shfl_xor(rs, 4); rs += __shfl_xor(rs, 8);
            l_run[r] = l_run[r] * al + rs;
            oacc[0][r] *= al; oacc[1][r] *= al;
            oacc[2][r] *= al; oacc[3][r] *= al;
            const int pb = (quad * 4 + r) * AP + ln16;
            Pw[wave][pb]      = f2bu(p0);
            Pw[wave][pb + 16] = f2bu(p1);
            Pw[wave][pb + 32] = f2bu(p2);
            Pw[wave][pb + 48] = f2bu(p3);
        }

        short8 pa0 = *(const short8*)&Pw[wave][ln16 * AP + quad * 8];
        short8 pa1 = *(const short8*)&Pw[wave][ln16 * AP + 32 + quad * 8];

#pragma unroll
        for (int j = 0; j < 4; j++) {
            const int drw = (j * 16 + ln16) * AP + quad * 8;
            short8 b0 = *(const short8*)&KsT[drw];
            short8 b1 = *(const short8*)&KsT[drw + 32];
            oacc[j] = __builtin_amdgcn_mfma_f32_16x16x32_bf16(pa0, b0, oacc[j], 0, 0, 0);
            oacc[j] = __builtin_amdgcn_mfma_f32_16x16x32_bf16(pa1, b1, oacc[j], 0, 0, 0);
        }
    }

#pragma unroll
    for (int r = 0; r < 4; r++) {
        const float inv = 1.0f / l_run[r];
        const int row = bb * SEQ + q0 + wave * 16 + quad * 4 + r;
#pragma unroll
        for (int j = 0; j < 4; j++) {
            const int col = hh * 64 + j * 16 + ln16;
            catb[(size_t)row * E2DIM + col] = f2bu(oacc[j][r] * inv);
        }
    }
}

// ---------------------------------------------------------------------------
// Host launch
// ---------------------------------------------------------------------------
extern "C" void kernel_launch(void* const* d_in, const int* in_sizes, int n_in,
                              void* d_out, int out_size, void* d_ws, size_t ws_size,
                              hipStream_t stream)
{
    // ---- workspace layout (float units) ----
    const size_t OFF_MT0 = 0;
    const size_t OFF_MT1 = OFF_MT0 + 131072;
    const size_t OFF_MT2 = OFF_MT1 + 131072;
    const size_t OFF_MT3 = OFF_MT2 + 131072;
    const size_t OFF_MT4 = OFF_MT3 + 131072;
    const size_t OFF_MT5 = OFF_MT4 + 524288;
    const size_t OFF_XB  = OFF_MT5 + 524288;        // x_bf / x1_bf (bf16 8192x512)
    const size_t OFF_CB  = OFF_XB + 2097152;        // cat bf16 [8192,1024]
    const size_t OFF_BQ  = OFF_CB + 4194304;        // q bf16 -> x2 bf16
    const size_t OFF_BN  = OFF_BQ + 4194304;        // fold t1 scratch -> h fp32
    const size_t OFF_BC  = OFF_BN + 4194304;        // fold t2 scratch -> x1 fp32
    const size_t OFF_P   = OFF_BC + 4194304;        // fp32-converted inputs

    float* W = (float*)d_ws;
    u16* MT[6] = {(u16*)(W + OFF_MT0), (u16*)(W + OFF_MT1), (u16*)(W + OFF_MT2),
                  (u16*)(W + OFF_MT3), (u16*)(W + OFF_MT4), (u16*)(W + OFF_MT5)};
    u16*   XB  = (u16*)(W + OFF_XB);
    u16*   CB  = (u16*)(W + OFF_CB);
    u16*   QB  = (u16*)(W + OFF_BQ);   // q bf16; later x2 bf16 (sequential reuse)
    float* BN  = W + OFF_BN;           // h fp32 (after fold)
    float* BC  = W + OFF_BC;           // x1 fp32 (after fold)

    float* F[23];
    CvtBatch cb;
    int pre = 0;
    for (int i = 0; i < 23 && i < n_in; i++) {
        cb.pre4[i] = pre;
        F[i] = W + OFF_P + (size_t)pre * 4;
        cb.src[i] = d_in[i];
        cb.dst[i] = (float4*)F[i];
        pre += in_sizes[i] / 4;
    }
    cb.pre4[23] = pre;
    const int total4 = pre;
    int* FLAG = (int*)(W + OFF_P + (size_t)total4 * 4);

    if (n_in < 23) return;
    if (ws_size < (OFF_P + (size_t)total4 * 4 + 16) * sizeof(float)) return;

    detect_dtype<<<1, 256, 0, stream>>>((const u16*)d_in[0], FLAG);
    cvt_all<<<(total4 + 255) / 256, 256, 0, stream>>>(cb, total4, FLAG);
    f2b_kernel<<<(ROWS * EDIM / 4 + 255) / 256, 256, 0, stream>>>(F[0], XB, ROWS * EDIM / 4);

    // ---- fold (3 batched launches): scratch overlays BN/BC (dead here) ----
    FoldBatch fb;
    {
        const int wi[6] = {1, 4, 7, 10, 13, 16};
        u16* T1 = (u16*)BN;
        u16* T2 = (u16*)BC;
        size_t off = 0;
        for (int s = 0; s < 6; s++) {
            const int n = (s < 4) ? 512 : 1024;
            fb.w[s]  = F[wi[s]];
            fb.fw[s] = F[wi[s] + 1];
            fb.t1[s] = T1 + off;
            fb.t2[s] = T2 + off;
            fb.mt[s] = MT[s];
            fb.n[s]  = n;
            fb.lg[s] = (s < 4) ? 9 : 10;
            fb.sc[s] = (s < 4) ? 0.04419417382415922f : 0.03125f;
            off += (size_t)n * n;
        }
    }
    fold_trconv<<<dim3(32, 32, 6), 256, 0, stream>>>(fb);
    fold_circ<<<dim3(4096, 1, 6), 256, 0, stream>>>(fb);
    fold_gemm<<<dim3(8, 8, 6), 256, 0, stream>>>(fb);

    float* out0 = (float*)d_out;                       // LN(h): [8192,512]
    float* out1 = (float*)d_out + (size_t)ROWS * EDIM; // out:   [8192,1024]

    // q = x @ M0 + attn_fb                                  -> QB (bf16)
    gemm_bf<<<dim3(4, 64), 256, 0, stream>>>(
        XB, 512, MT[0], 512, F[3], nullptr, 0, QB, 512, nullptr, 0, nullptr, 0, 512, 0);
    // attention -> cat bf16 [:, :512]
    attn_mfma<<<1024, 256, 0, stream>>>(QB, CB);
    // x1 = LN(x + newx; n1)                                 -> BC fp32 + XB bf16
    ln_kernel<<<8192, 256, 0, stream>>>(F[0], 512, CB, 1024, F[19], F[20],
                                        BC, 512, XB, 512);
    // x_ln = gelu(x1 @ M1 + b); cat[:,512:]=bf16(v); x2=bf16(x1-v) -> QB
    gemm_bf<<<dim3(4, 64), 256, 0, stream>>>(
        XB, 512, MT[1], 512, F[6], nullptr, 0, CB + 512, 1024, QB, 512, BC, 512, 512, 1);
    // h = sigmoid(x2@M2+b2) * (x2@M3+b3)                     -> BN fp32
    gemm_bf2<<<dim3(4, 64), 256, 0, stream>>>(
        QB, 512, MT[2], MT[3], 512, F[9], F[12], BN, 512, 512);
    // out0 = LN(h; n2)                                       -> d_out
    ln_kernel<<<8192, 256, 0, stream>>>(BN, 512, nullptr, 0, F[21], F[22],
                                        out0, 512, nullptr, 0);
    // out1 = sigmoid(cat@M4+b4) * (cat@M5+b5)                -> d_out+4M
    gemm_bf2<<<dim3(8, 64), 256, 0, stream>>>(
        CB, 1024, MT[4], MT[5], 1024, F[15], F[18], out1, 1024, 1024);
}

// Round 2
// 414.591 us; speedup vs baseline: 1.1041x; 1.0921x over previous
//
#include <hip/hip_runtime.h>
#include <hip/hip_bf16.h>
#include <math.h>

typedef __hip_bfloat16 bf16;
typedef unsigned short u16;
typedef __attribute__((ext_vector_type(8))) short short8;
typedef __attribute__((ext_vector_type(4))) float f32x4;

#define NB      8
#define SEQ     1024
#define EDIM    512
#define E2DIM   1024
#define ROWS    8192
#define INV_SQRT_E 0.04419417382415922f
#define ATT_SCL    0.06375985678148161f   /* INV_SQRT_E * log2(e) */

__device__ inline u16 f2bu(float f) {           // fp32 -> bf16 bits, RNE
    union { float f; unsigned u; } c; c.f = f;
    return (u16)((c.u + 0x7FFF + ((c.u >> 16) & 1)) >> 16);
}

// ---------------------------------------------------------------------------
// Input dtype autodetect (proved inputs are fp32; kept as cheap insurance).
// ---------------------------------------------------------------------------
__global__ __launch_bounds__(256) void detect_dtype(const u16* __restrict__ x,
                                                    int* __restrict__ flag) {
    int t = threadIdx.x;
    int cnt = 0;
    for (int k = t; k < 8192; k += 256) {
        int e = (x[k] >> 7) & 0xFF;
        if (e >= 0xC0) cnt++;
    }
#pragma unroll
    for (int o = 32; o > 0; o >>= 1) cnt += __shfl_xor(cnt, o);
    __shared__ int red[4];
    if ((t & 63) == 0) red[t >> 6] = cnt;
    __syncthreads();
    if (t == 0) flag[0] = (red[0] + red[1] + red[2] + red[3] > 100) ? 1 : 0;
}

// ---------------------------------------------------------------------------
// Batch conversion of all 23 inputs -> fp32 workspace (dtype-adaptive).
// ---------------------------------------------------------------------------
struct CvtBatch {
    const void* src[23];
    float4*     dst[23];
    int         pre4[24];
};

__global__ __launch_bounds__(256) void cvt_all(CvtBatch a, int total4,
                                               const int* __restrict__ flag) {
    int t = blockIdx.x * 256 + threadIdx.x;
    if (t >= total4) return;
    int lo = 0;
    while (t >= a.pre4[lo + 1]) lo++;
    int li = t - a.pre4[lo];
    if (flag[0]) {
        a.dst[lo][li] = ((const float4*)a.src[lo])[li];
    } else {
        ushort4 u = ((const ushort4*)a.src[lo])[li];
        union { unsigned int i; float f; } c;
        float4 o;
        c.i = ((unsigned)u.x) << 16; o.x = c.f;
        c.i = ((unsigned)u.y) << 16; o.y = c.f;
        c.i = ((unsigned)u.z) << 16; o.z = c.f;
        c.i = ((unsigned)u.w) << 16; o.w = c.f;
        a.dst[lo][li] = o;
    }
}

// fp32 -> bf16 elementwise, n/4 threads
__global__ __launch_bounds__(256) void f2b_kernel(const float* __restrict__ src,
                                                  u16* __restrict__ dst, int n4) {
    int i = blockIdx.x * 256 + threadIdx.x;
    if (i >= n4) return;
    float4 a = ((const float4*)src)[i];
    ushort4 o;
    o.x = f2bu(a.x); o.y = f2bu(a.y); o.z = f2bu(a.z); o.w = f2bu(a.w);
    ((ushort4*)dst)[i] = o;
}

// ---------------------------------------------------------------------------
// async global->LDS staging of a 128x32 bf16 tile (linear LDS, width=16).
// LDS dest is wave-uniform base + lane*16 (HW rule); global src is per-lane.
// ---------------------------------------------------------------------------
#define LDK 32   /* linear LDS row: 32 bf16 = 64 B */

__device__ __forceinline__ void stage128x32(const u16* g, int ld, u16* lds, int tid) {
    const int w = tid >> 6;              // wave id (uniform within wave)
    const int l = tid & 63;
    const int r = w * 16 + (l >> 2);     // row covered by this lane
    const int c = (l & 3) * 8;           // 16B chunk within row
    const u16* g0 = g + (size_t)r * ld + c;
    u16* l0 = lds + w * 16 * LDK;        // wave-uniform LDS base
    __builtin_amdgcn_global_load_lds(
        (const __attribute__((address_space(1))) void*)g0,
        (__attribute__((address_space(3))) void*)l0, 16, 0, 0);
    const u16* g1 = g0 + (size_t)64 * ld;
    u16* l1 = l0 + 64 * LDK;
    __builtin_amdgcn_global_load_lds(
        (const __attribute__((address_space(1))) void*)g1,
        (__attribute__((address_space(3))) void*)l1, 16, 0, 0);
}

// Bijective XCD-aware block swizzle (requires gridDim.x*gridDim.y % 8 == 0;
// all launches using it are 256 or 512 blocks). Consecutive by-rows land on
// the same XCD L2 so the shared A-panel is fetched once per XCD, not 8x.
__device__ __forceinline__ void xcd_swz(int& bx, int& by) {
    const int nx  = gridDim.x;
    const int nwg = nx * gridDim.y;
    const int lid = blockIdx.y * nx + blockIdx.x;
    const int q   = nwg >> 3;
    const int s   = (lid & 7) * q + (lid >> 3);
    bx = s % nx;
    by = s / nx;
}

// ---------------------------------------------------------------------------
// Fold batch: 6 spectral layers, z-indexed kernels (3 launches total).
// Mt[s][o][j] = sc * sum_m fw[m][o] * w[(m-j) mod n]
// ---------------------------------------------------------------------------
struct FoldBatch {
    const float* w[6];
    const float* fw[6];
    u16* t1[6];    // fwT bf16: t1[o][m] = bf16(fw[m][o])
    u16* t2[6];    // circ bf16: t2[j][m] = bf16(w[(m-j) mod n])
    u16* mt[6];    // output Mt bf16 [n][n]
    int  n[6], lg[6];
    float sc[6];
};

__global__ __launch_bounds__(256) void fold_trconv(FoldBatch fb) {
    const int z = blockIdx.z;
    const int n = fb.n[z];
    const int bx = blockIdx.x * 32, by = blockIdx.y * 32;
    if (bx >= n || by >= n) return;
    __shared__ float t[32][33];
    const int tx = threadIdx.x & 31, ty = threadIdx.x >> 5;   // 32x8
    const float* src = fb.fw[z];
    u16* dst = fb.t1[z];
#pragma unroll
    for (int r = 0; r < 32; r += 8)
        t[ty + r][tx] = src[(size_t)(by + ty + r) * n + bx + tx];
    __syncthreads();
#pragma unroll
    for (int r = 0; r < 32; r += 8)
        dst[(size_t)(bx + ty + r) * n + by + tx] = f2bu(t[tx][ty + r]);
}

__global__ __launch_bounds__(256) void fold_circ(FoldBatch fb) {
    const int z = blockIdx.z;
    const int n = fb.n[z], lg = fb.lg[z];
    int idx = blockIdx.x * 256 + threadIdx.x;
    if (idx >= n * n) return;
    int mask = n - 1;
    int m = idx & mask;
    int j = idx >> lg;
    fb.t2[z][idx] = f2bu(fb.w[z][(m - j) & mask]);
}

__global__ __launch_bounds__(256) void fold_gemm(FoldBatch fb) {
    const int z = blockIdx.z;
    const int n = fb.n[z];
    const int bm = blockIdx.y * 128, bn = blockIdx.x * 128;
    if (bm >= n || bn >= n) return;
    const u16* A  = fb.t1[z];
    const u16* Bt = fb.t2[z];
    u16* Mt = fb.mt[z];
    const float scale = fb.sc[z];

    __shared__ u16 Asl[2][128 * LDK];
    __shared__ u16 Bsl[2][128 * LDK];
    const int tid = threadIdx.x;
    const int lane = tid & 63, wave = tid >> 6;
    const int wy = wave >> 1, wx = wave & 1;
    const int qd = lane >> 4, ln16 = lane & 15;

    f32x4 acc[4][4];
#pragma unroll
    for (int i = 0; i < 4; i++)
#pragma unroll
        for (int j = 0; j < 4; j++)
#pragma unroll
            for (int r = 0; r < 4; r++) acc[i][j][r] = 0.f;

    const u16* Ab = A  + (size_t)bm * n;
    const u16* Bb = Bt + (size_t)bn * n;
    stage128x32(Ab, n, Asl[0], tid);
    stage128x32(Bb, n, Bsl[0], tid);
    __syncthreads();
    int cur = 0;
    for (int k0 = 0; k0 < n; k0 += 32) {
        if (k0 + 32 < n) {                       // prefetch next tile (async)
            stage128x32(Ab + k0 + 32, n, Asl[cur ^ 1], tid);
            stage128x32(Bb + k0 + 32, n, Bsl[cur ^ 1], tid);
        }
        const u16* Ac = Asl[cur];
        const u16* Bc = Bsl[cur];
        short8 af[4], bf_[4];
#pragma unroll
        for (int i = 0; i < 4; i++) {
            af[i]  = *(const short8*)&Ac[(wy * 64 + i * 16 + ln16) * LDK + qd * 8];
            bf_[i] = *(const short8*)&Bc[(wx * 64 + i * 16 + ln16) * LDK + qd * 8];
        }
#pragma unroll
        for (int i = 0; i < 4; i++)
#pragma unroll
            for (int j = 0; j < 4; j++)
                acc[i][j] = __builtin_amdgcn_mfma_f32_16x16x32_bf16(af[i], bf_[j], acc[i][j], 0, 0, 0);
        __syncthreads();                         // drains prefetch + guards swap
        cur ^= 1;
    }
#pragma unroll
    for (int i = 0; i < 4; i++)
#pragma unroll
        for (int j = 0; j < 4; j++) {
            const int col = bn + wx * 64 + j * 16 + ln16;
#pragma unroll
            for (int r = 0; r < 4; r++) {
                const int row = bm + wy * 64 + i * 16 + qd * 4 + r;
                Mt[(size_t)row * n + col] = f2bu(acc[i][j][r] * scale);
            }
        }
}

// ---------------------------------------------------------------------------
// bf16 MFMA GEMM (single B): C = act( A @ B + bias ). B pre-transposed.
// 128x128 tile, BK=32, 4 waves, async staging + dbuf prefetch, 1 barrier/iter.
// mode: 0 none, 1 gelu(exact). Optional outputs: Cf fp32, Cb bf16(v),
// Cb2 bf16(aux - v).
// ---------------------------------------------------------------------------
__global__ __launch_bounds__(256) void gemm_bf(
    const u16* __restrict__ A, int lda,
    const u16* __restrict__ Bt, int ldb,
    const float* __restrict__ bias,
    float* __restrict__ Cf, int ldc,
    u16* __restrict__ Cb, int ldcb,
    u16* __restrict__ Cb2, int ldcb2,
    const float* __restrict__ aux, int ldaux,
    int K, int mode)
{
    __shared__ u16 Asl[2][128 * LDK];
    __shared__ u16 Bsl[2][128 * LDK];
    const int tid = threadIdx.x;
    int bxs, bys;
    xcd_swz(bxs, bys);
    const int bm = bys * 128, bn = bxs * 128;
    const int lane = tid & 63, wave = tid >> 6;
    const int wy = wave >> 1, wx = wave & 1;
    const int qd = lane >> 4, ln16 = lane & 15;

    f32x4 acc[4][4];
#pragma unroll
    for (int i = 0; i < 4; i++)
#pragma unroll
        for (int j = 0; j < 4; j++)
#pragma unroll
            for (int r = 0; r < 4; r++) acc[i][j][r] = 0.f;

    const u16* Ab = A  + (size_t)bm * lda;
    const u16* Bb = Bt + (size_t)bn * ldb;
    stage128x32(Ab, lda, Asl[0], tid);
    stage128x32(Bb, ldb, Bsl[0], tid);
    __syncthreads();
    int cur = 0;
    for (int k0 = 0; k0 < K; k0 += 32) {
        if (k0 + 32 < K) {
            stage128x32(Ab + k0 + 32, lda, Asl[cur ^ 1], tid);
            stage128x32(Bb + k0 + 32, ldb, Bsl[cur ^ 1], tid);
        }
        const u16* Ac = Asl[cur];
        const u16* Bc = Bsl[cur];
        short8 af[4], bf_[4];
#pragma unroll
        for (int i = 0; i < 4; i++) {
            af[i]  = *(const short8*)&Ac[(wy * 64 + i * 16 + ln16) * LDK + qd * 8];
            bf_[i] = *(const short8*)&Bc[(wx * 64 + i * 16 + ln16) * LDK + qd * 8];
        }
#pragma unroll
        for (int i = 0; i < 4; i++)
#pragma unroll
            for (int j = 0; j < 4; j++)
                acc[i][j] = __builtin_amdgcn_mfma_f32_16x16x32_bf16(af[i], bf_[j], acc[i][j], 0, 0, 0);
        __syncthreads();
        cur ^= 1;
    }

#pragma unroll
    for (int i = 0; i < 4; i++) {
#pragma unroll
        for (int j = 0; j < 4; j++) {
            const int col = bn + wx * 64 + j * 16 + ln16;
            const float b_ = bias ? bias[col] : 0.f;
#pragma unroll
            for (int r = 0; r < 4; r++) {
                const int row = bm + wy * 64 + i * 16 + qd * 4 + r;
                float v = acc[i][j][r] + b_;
                if (mode == 1) v = 0.5f * v * (1.0f + erff(v * 0.7071067811865476f));
                if (Cf)  Cf[(size_t)row * ldc + col] = v;
                if (Cb)  Cb[(size_t)row * ldcb + col] = f2bu(v);
                if (Cb2) Cb2[(size_t)row * ldcb2 + col] =
                             f2bu(aux[(size_t)row * ldaux + col] - v);
            }
        }
    }
}

// ---------------------------------------------------------------------------
// Dual-B fused gate GEMM: C = sigmoid(A@B1 + b1) * (A@B2 + b2), fp32 out.
// Same tile structure, A staged once, 32 MFMA/iter/wave, dbuf prefetch.
// ---------------------------------------------------------------------------
__global__ __launch_bounds__(256) void gemm_bf2(
    const u16* __restrict__ A, int lda,
    const u16* __restrict__ B1t, const u16* __restrict__ B2t, int ldb,
    const float* __restrict__ bias1, const float* __restrict__ bias2,
    float* __restrict__ Cf, int ldc, int K)
{
    __shared__ u16 Asl[2][128 * LDK];
    __shared__ u16 B1sl[2][128 * LDK];
    __shared__ u16 B2sl[2][128 * LDK];
    const int tid = threadIdx.x;
    int bxs, bys;
    xcd_swz(bxs, bys);
    const int bm = bys * 128, bn = bxs * 128;
    const int lane = tid & 63, wave = tid >> 6;
    const int wy = wave >> 1, wx = wave & 1;
    const int qd = lane >> 4, ln16 = lane & 15;

    f32x4 acc1[4][4], acc2[4][4];
#pragma unroll
    for (int i = 0; i < 4; i++)
#pragma unroll
        for (int j = 0; j < 4; j++)
#pragma unroll
            for (int r = 0; r < 4; r++) { acc1[i][j][r] = 0.f; acc2[i][j][r] = 0.f; }

    const u16* Ab  = A   + (size_t)bm * lda;
    const u16* B1b = B1t + (size_t)bn * ldb;
    const u16* B2b = B2t + (size_t)bn * ldb;
    stage128x32(Ab,  lda, Asl[0],  tid);
    stage128x32(B1b, ldb, B1sl[0], tid);
    stage128x32(B2b, ldb, B2sl[0], tid);
    __syncthreads();
    int cur = 0;
    for (int k0 = 0; k0 < K; k0 += 32) {
        if (k0 + 32 < K) {
            stage128x32(Ab  + k0 + 32, lda, Asl[cur ^ 1],  tid);
            stage128x32(B1b + k0 + 32, ldb, B1sl[cur ^ 1], tid);
            stage128x32(B2b + k0 + 32, ldb, B2sl[cur ^ 1], tid);
        }
        const u16* Ac  = Asl[cur];
        const u16* B1c = B1sl[cur];
        const u16* B2c = B2sl[cur];
        short8 af[4], b1f[4], b2f[4];
#pragma unroll
        for (int i = 0; i < 4; i++) {
            af[i]  = *(const short8*)&Ac [(wy * 64 + i * 16 + ln16) * LDK + qd * 8];
            b1f[i] = *(const short8*)&B1c[(wx * 64 + i * 16 + ln16) * LDK + qd * 8];
            b2f[i] = *(const short8*)&B2c[(wx * 64 + i * 16 + ln16) * LDK + qd * 8];
        }
#pragma unroll
        for (int i = 0; i < 4; i++)
#pragma unroll
            for (int j = 0; j < 4; j++) {
                acc1[i][j] = __builtin_amdgcn_mfma_f32_16x16x32_bf16(af[i], b1f[j], acc1[i][j], 0, 0, 0);
                acc2[i][j] = __builtin_amdgcn_mfma_f32_16x16x32_bf16(af[i], b2f[j], acc2[i][j], 0, 0, 0);
            }
        __syncthreads();
        cur ^= 1;
    }

#pragma unroll
    for (int i = 0; i < 4; i++) {
#pragma unroll
        for (int j = 0; j < 4; j++) {
            const int col = bn + wx * 64 + j * 16 + ln16;
            const float b1_ = bias1[col], b2_ = bias2[col];
#pragma unroll
            for (int r = 0; r < 4; r++) {
                const int row = bm + wy * 64 + i * 16 + qd * 4 + r;
                const float g = 1.0f / (1.0f + expf(-(acc1[i][j][r] + b1_)));
                Cf[(size_t)row * ldc + col] = g * (acc2[i][j][r] + b2_);
            }
        }
    }
}

// ---------------------------------------------------------------------------
// LayerNorm over 512 features. in1b optional bf16 add. fp32 + optional bf16 out.
// ---------------------------------------------------------------------------
__global__ __launch_bounds__(256) void ln_kernel(
    const float* __restrict__ in0, int ld0,
    const u16* __restrict__ in1b, int ld1b,
    const float* __restrict__ g, const float* __restrict__ bta,
    float* __restrict__ outf, int ldo,
    u16* __restrict__ outb, int ldob)
{
    int row = blockIdx.x, tid = threadIdx.x;
    const float* p0 = in0 + (size_t)row * ld0;
    float v0 = p0[tid], v1 = p0[tid + 256];
    if (in1b) {
        const u16* p1 = in1b + (size_t)row * ld1b;
        union { unsigned u; float f; } c0, c1;
        c0.u = ((unsigned)p1[tid]) << 16;
        c1.u = ((unsigned)p1[tid + 256]) << 16;
        v0 += c0.f; v1 += c1.f;
    }
    float s = v0 + v1, sq = v0 * v0 + v1 * v1;
#pragma unroll
    for (int o = 32; o > 0; o >>= 1) {
        s  += __shfl_xor(s, o);
        sq += __shfl_xor(sq, o);
    }
    __shared__ float red[8];
    int wid = tid >> 6;
    if ((tid & 63) == 0) { red[wid] = s; red[4 + wid] = sq; }
    __syncthreads();
    s  = red[0] + red[1] + red[2] + red[3];
    sq = red[4] + red[5] + red[6] + red[7];
    float mean = s * (1.0f / 512.0f);
    float var  = sq * (1.0f / 512.0f) - mean * mean;
    float rstd = rsqrtf(var + 1e-5f);
    float o0 = (v0 - mean) * rstd * g[tid] + bta[tid];
    float o1 = (v1 - mean) * rstd * g[tid + 256] + bta[tid + 256];
    if (outf) {
        outf[(size_t)row * ldo + tid]       = o0;
        outf[(size_t)row * ldo + tid + 256] = o1;
    }
    if (outb) {
        outb[(size_t)row * ldob + tid]       = f2bu(o0);
        outb[(size_t)row * ldob + tid + 256] = f2bu(o1);
    }
}

// ---------------------------------------------------------------------------
// MFMA flash attention, q==k==v bf16, head_dim 64. exp2-domain softmax.
// Writes bf16 new_x into catb[:, 0:512] (ld 1024).
// ---------------------------------------------------------------------------
#define AP 72   /* LDS pitch in bf16 elems */

__global__ __launch_bounds__(256) void attn_mfma(const u16* __restrict__ qall,
                                                 u16* __restrict__ catb) {
    __shared__ u16 Ks[64 * AP];        // [key][d]
    __shared__ u16 KsT[64 * AP];       // [d][key]
    __shared__ u16 Pw[4][16 * AP];     // per-wave P [row][key]

    const int bid = blockIdx.x;
    const int lt = bid & 15, hh = (bid >> 4) & 7, bb = bid >> 7;
    const int q0 = lt * 64;
    const int tid = threadIdx.x;
    const int wave = tid >> 6, lane = tid & 63;
    const int quad = lane >> 4, ln16 = lane & 15;

    const u16* qh = qall + (size_t)bb * SEQ * EDIM + hh * 64;

    const u16* qrow = qh + (size_t)(q0 + wave * 16 + ln16) * EDIM + quad * 8;
    const short8 aq0 = *(const short8*)(qrow);
    const short8 aq1 = *(const short8*)(qrow + 32);

    f32x4 oacc[4];
    float m_run[4], l_run[4];
#pragma unroll
    for (int j = 0; j < 4; j++)
#pragma unroll
        for (int r = 0; r < 4; r++) oacc[j][r] = 0.f;
#pragma unroll
    for (int r = 0; r < 4; r++) { m_run[r] = -1e30f; l_run[r] = 0.f; }

    const int sr  = tid & 63;
    const int scq = (tid >> 6) * 16;

    for (int s0 = 0; s0 < SEQ; s0 += 64) {
        __syncthreads();
        {
            const u16* krow = qh + (size_t)(s0 + sr) * EDIM + scq;
            uint4 v0 = *(const uint4*)(krow);
            uint4 v1 = *(const uint4*)(krow + 8);
            *(uint4*)&Ks[sr * AP + scq]     = v0;
            *(uint4*)&Ks[sr * AP + scq + 8] = v1;
            const u16* h0 = (const u16*)&v0;
            const u16* h1 = (const u16*)&v1;
#pragma unroll
            for (int i = 0; i < 8; i++) KsT[(scq + i) * AP + sr]     = h0[i];
#pragma unroll
            for (int i = 0; i < 8; i++) KsT[(scq + 8 + i) * AP + sr] = h1[i];
        }
        __syncthreads();

        f32x4 S[4];
#pragma unroll
        for (int j = 0; j < 4; j++) {
            const int krw = (j * 16 + ln16) * AP + quad * 8;
            short8 b0 = *(const short8*)&Ks[krw];
            short8 b1 = *(const short8*)&Ks[krw + 32];
            f32x4 c = {0.f, 0.f, 0.f, 0.f};
            c = __builtin_amdgcn_mfma_f32_16x16x32_bf16(aq0, b0, c, 0, 0, 0);
            c = __builtin_amdgcn_mfma_f32_16x16x32_bf16(aq1, b1, c, 0, 0, 0);
            S[j] = c;
        }

#pragma unroll
        for (int r = 0; r < 4; r++) {
            float v0_ = S[0][r] * ATT_SCL;       // log2-domain scores
            float v1_ = S[1][r] * ATT_SCL;
            float v2_ = S[2][r] * ATT_SCL;
            float v3_ = S[3][r] * ATT_SCL;
            float mx = fmaxf(fmaxf(v0_, v1_), fmaxf(v2_, v3_));
            mx = fmaxf(mx, __shfl_xor(mx, 1));
            mx = fmaxf(mx, __shfl_xor(mx, 2));
            mx = fmaxf(mx, __shfl_xor(mx, 4));
            mx = fmaxf(mx, __shfl_xor(mx, 8));
            float mn = fmaxf(m_run[r], mx);
            float al = exp2f(m_run[r] - mn);
            m_run[r] = mn;
            float p0 = exp2f(v0_ - mn), p1 = exp2f(v1_ - mn);
            float p2 = exp2f(v2_ - mn), p3 = exp2f(v3_ - mn);
            float rs = p0 + p1 + p2 + p3;
            rs += __shfl_xor(rs, 1); rs += __shfl_xor(rs, 2);
            rs += __shfl_xor(rs, 4); rs += __shfl_xor(rs, 8);
            l_run[r] = l_run[r] * al + rs;
            oacc[0][r] *= al; oacc[1][r] *= al;
            oacc[2][r] *= al; oacc[3][r] *= al;
            const int pb = (quad * 4 + r) * AP + ln16;
            Pw[wave][pb]      = f2bu(p0);
            Pw[wave][pb + 16] = f2bu(p1);
            Pw[wave][pb + 32] = f2bu(p2);
            Pw[wave][pb + 48] = f2bu(p3);
        }

        short8 pa0 = *(const short8*)&Pw[wave][ln16 * AP + quad * 8];
        short8 pa1 = *(const short8*)&Pw[wave][ln16 * AP + 32 + quad * 8];

#pragma unroll
        for (int j = 0; j < 4; j++) {
            const int drw = (j * 16 + ln16) * AP + quad * 8;
            short8 b0 = *(const short8*)&KsT[drw];
            short8 b1 = *(const short8*)&KsT[drw + 32];
            oacc[j] = __builtin_amdgcn_mfma_f32_16x16x32_bf16(pa0, b0, oacc[j], 0, 0, 0);
            oacc[j] = __builtin_amdgcn_mfma_f32_16x16x32_bf16(pa1, b1, oacc[j], 0, 0, 0);
        }
    }

#pragma unroll
    for (int r = 0; r < 4; r++) {
        const float inv = 1.0f / l_run[r];
        const int row = bb * SEQ + q0 + wave * 16 + quad * 4 + r;
#pragma unroll
        for (int j = 0; j < 4; j++) {
            const int col = hh * 64 + j * 16 + ln16;
            catb[(size_t)row * E2DIM + col] = f2bu(oacc[j][r] * inv);
        }
    }
}

// ---------------------------------------------------------------------------
// Host launch
// ---------------------------------------------------------------------------
extern "C" void kernel_launch(void* const* d_in, const int* in_sizes, int n_in,
                              void* d_out, int out_size, void* d_ws, size_t ws_size,
                              hipStream_t stream)
{
    // ---- workspace layout (float units) ----
    const size_t OFF_MT0 = 0;
    const size_t OFF_MT1 = OFF_MT0 + 131072;
    const size_t OFF_MT2 = OFF_MT1 + 131072;
    const size_t OFF_MT3 = OFF_MT2 + 131072;
    const size_t OFF_MT4 = OFF_MT3 + 131072;
    const size_t OFF_MT5 = OFF_MT4 + 524288;
    const size_t OFF_XB  = OFF_MT5 + 524288;        // x_bf / x1_bf (bf16 8192x512)
    const size_t OFF_CB  = OFF_XB + 2097152;        // cat bf16 [8192,1024]
    const size_t OFF_BQ  = OFF_CB + 4194304;        // q bf16 -> x2 bf16
    const size_t OFF_BN  = OFF_BQ + 4194304;        // fold t1 scratch -> h fp32
    const size_t OFF_BC  = OFF_BN + 4194304;        // fold t2 scratch -> x1 fp32
    const size_t OFF_P   = OFF_BC + 4194304;        // fp32-converted inputs

    float* W = (float*)d_ws;
    u16* MT[6] = {(u16*)(W + OFF_MT0), (u16*)(W + OFF_MT1), (u16*)(W + OFF_MT2),
                  (u16*)(W + OFF_MT3), (u16*)(W + OFF_MT4), (u16*)(W + OFF_MT5)};
    u16*   XB  = (u16*)(W + OFF_XB);
    u16*   CB  = (u16*)(W + OFF_CB);
    u16*   QB  = (u16*)(W + OFF_BQ);   // q bf16; later x2 bf16 (sequential reuse)
    float* BN  = W + OFF_BN;           // h fp32 (after fold)
    float* BC  = W + OFF_BC;           // x1 fp32 (after fold)

    float* F[23];
    CvtBatch cb;
    int pre = 0;
    for (int i = 0; i < 23 && i < n_in; i++) {
        cb.pre4[i] = pre;
        F[i] = W + OFF_P + (size_t)pre * 4;
        cb.src[i] = d_in[i];
        cb.dst[i] = (float4*)F[i];
        pre += in_sizes[i] / 4;
    }
    cb.pre4[23] = pre;
    const int total4 = pre;
    int* FLAG = (int*)(W + OFF_P + (size_t)total4 * 4);

    if (n_in < 23) return;
    if (ws_size < (OFF_P + (size_t)total4 * 4 + 16) * sizeof(float)) return;

    detect_dtype<<<1, 256, 0, stream>>>((const u16*)d_in[0], FLAG);
    cvt_all<<<(total4 + 255) / 256, 256, 0, stream>>>(cb, total4, FLAG);
    f2b_kernel<<<(ROWS * EDIM / 4 + 255) / 256, 256, 0, stream>>>(F[0], XB, ROWS * EDIM / 4);

    // ---- fold (3 batched launches): scratch overlays BN/BC (dead here) ----
    FoldBatch fb;
    {
        const int wi[6] = {1, 4, 7, 10, 13, 16};
        u16* T1 = (u16*)BN;
        u16* T2 = (u16*)BC;
        size_t off = 0;
        for (int s = 0; s < 6; s++) {
            const int n = (s < 4) ? 512 : 1024;
            fb.w[s]  = F[wi[s]];
            fb.fw[s] = F[wi[s] + 1];
            fb.t1[s] = T1 + off;
            fb.t2[s] = T2 + off;
            fb.mt[s] = MT[s];
            fb.n[s]  = n;
            fb.lg[s] = (s < 4) ? 9 : 10;
            fb.sc[s] = (s < 4) ? 0.04419417382415922f : 0.03125f;
            off += (size_t)n * n;
        }
    }
    fold_trconv<<<dim3(32, 32, 6), 256, 0, stream>>>(fb);
    fold_circ<<<dim3(4096, 1, 6), 256, 0, stream>>>(fb);
    fold_gemm<<<dim3(8, 8, 6), 256, 0, stream>>>(fb);

    float* out0 = (float*)d_out;                       // LN(h): [8192,512]
    float* out1 = (float*)d_out + (size_t)ROWS * EDIM; // out:   [8192,1024]

    // q = x @ M0 + attn_fb                                  -> QB (bf16)
    gemm_bf<<<dim3(4, 64), 256, 0, stream>>>(
        XB, 512, MT[0], 512, F[3], nullptr, 0, QB, 512, nullptr, 0, nullptr, 0, 512, 0);
    // attention -> cat bf16 [:, :512]
    attn_mfma<<<1024, 256, 0, stream>>>(QB, CB);
    // x1 = LN(x + newx; n1)                                 -> BC fp32 + XB bf16
    ln_kernel<<<8192, 256, 0, stream>>>(F[0], 512, CB, 1024, F[19], F[20],
                                        BC, 512, XB, 512);
    // x_ln = gelu(x1 @ M1 + b); cat[:,512:]=bf16(v); x2=bf16(x1-v) -> QB
    gemm_bf<<<dim3(4, 64), 256, 0, stream>>>(
        XB, 512, MT[1], 512, F[6], nullptr, 0, CB + 512, 1024, QB, 512, BC, 512, 512, 1);
    // h = sigmoid(x2@M2+b2) * (x2@M3+b3)                     -> BN fp32
    gemm_bf2<<<dim3(4, 64), 256, 0, stream>>>(
        QB, 512, MT[2], MT[3], 512, F[9], F[12], BN, 512, 512);
    // out0 = LN(h; n2)                                       -> d_out
    ln_kernel<<<8192, 256, 0, stream>>>(BN, 512, nullptr, 0, F[21], F[22],
                                        out0, 512, nullptr, 0);
    // out1 = sigmoid(cat@M4+b4) * (cat@M5+b5)                -> d_out+4M
    gemm_bf2<<<dim3(8, 64), 256, 0, stream>>>(
        CB, 1024, MT[4], MT[5], 1024, F[15], F[18], out1, 1024, 1024);
}

// Round 3
// 371.342 us; speedup vs baseline: 1.2327x; 1.1165x over previous
//
#include <hip/hip_runtime.h>
#include <hip/hip_bf16.h>
#include <math.h>

typedef __hip_bfloat16 bf16;
typedef unsigned short u16;
typedef __attribute__((ext_vector_type(8))) short short8;
typedef __attribute__((ext_vector_type(4))) float f32x4;

#define NB      8
#define SEQ     1024
#define EDIM    512
#define E2DIM   1024
#define ROWS    8192
#define INV_SQRT_E 0.04419417382415922f
#define ATT_SCL    0.06375985678148161f   /* INV_SQRT_E * log2(e) */

__device__ inline u16 f2bu(float f) {           // fp32 -> bf16 bits, RNE
    union { float f; unsigned u; } c; c.f = f;
    return (u16)((c.u + 0x7FFF + ((c.u >> 16) & 1)) >> 16);
}

// ---------------------------------------------------------------------------
// Input dtype autodetect (proved inputs are fp32; kept as cheap insurance).
// ---------------------------------------------------------------------------
__global__ __launch_bounds__(256) void detect_dtype(const u16* __restrict__ x,
                                                    int* __restrict__ flag) {
    int t = threadIdx.x;
    int cnt = 0;
    for (int k = t; k < 8192; k += 256) {
        int e = (x[k] >> 7) & 0xFF;
        if (e >= 0xC0) cnt++;
    }
#pragma unroll
    for (int o = 32; o > 0; o >>= 1) cnt += __shfl_xor(cnt, o);
    __shared__ int red[4];
    if ((t & 63) == 0) red[t >> 6] = cnt;
    __syncthreads();
    if (t == 0) flag[0] = (red[0] + red[1] + red[2] + red[3] > 100) ? 1 : 0;
}

// ---------------------------------------------------------------------------
// Batch conversion of all 23 inputs -> fp32 workspace (dtype-adaptive).
// ---------------------------------------------------------------------------
struct CvtBatch {
    const void* src[23];
    float4*     dst[23];
    int         pre4[24];
};

__global__ __launch_bounds__(256) void cvt_all(CvtBatch a, int total4,
                                               const int* __restrict__ flag) {
    int t = blockIdx.x * 256 + threadIdx.x;
    if (t >= total4) return;
    int lo = 0;
    while (t >= a.pre4[lo + 1]) lo++;
    int li = t - a.pre4[lo];
    if (flag[0]) {
        a.dst[lo][li] = ((const float4*)a.src[lo])[li];
    } else {
        ushort4 u = ((const ushort4*)a.src[lo])[li];
        union { unsigned int i; float f; } c;
        float4 o;
        c.i = ((unsigned)u.x) << 16; o.x = c.f;
        c.i = ((unsigned)u.y) << 16; o.y = c.f;
        c.i = ((unsigned)u.z) << 16; o.z = c.f;
        c.i = ((unsigned)u.w) << 16; o.w = c.f;
        a.dst[lo][li] = o;
    }
}

// fp32 -> bf16 elementwise, n/4 threads
__global__ __launch_bounds__(256) void f2b_kernel(const float* __restrict__ src,
                                                  u16* __restrict__ dst, int n4) {
    int i = blockIdx.x * 256 + threadIdx.x;
    if (i >= n4) return;
    float4 a = ((const float4*)src)[i];
    ushort4 o;
    o.x = f2bu(a.x); o.y = f2bu(a.y); o.z = f2bu(a.z); o.w = f2bu(a.w);
    ((ushort4*)dst)[i] = o;
}

// ---------------------------------------------------------------------------
// async global->LDS staging (linear LDS, width=16).
// LDS dest is wave-uniform base + lane*16 (HW rule); global src is per-lane.
// ---------------------------------------------------------------------------
#define LDK 32   /* linear LDS row: 32 bf16 = 64 B */

__device__ __forceinline__ void stage128x32(const u16* g, int ld, u16* lds, int tid) {
    const int w = tid >> 6;              // wave id (uniform within wave)
    const int l = tid & 63;
    const int r = w * 16 + (l >> 2);     // row covered by this lane
    const int c = (l & 3) * 8;           // 16B chunk within row
    const u16* g0 = g + (size_t)r * ld + c;
    u16* l0 = lds + w * 16 * LDK;        // wave-uniform LDS base
    __builtin_amdgcn_global_load_lds(
        (const __attribute__((address_space(1))) void*)g0,
        (__attribute__((address_space(3))) void*)l0, 16, 0, 0);
    const u16* g1 = g0 + (size_t)64 * ld;
    u16* l1 = l0 + 64 * LDK;
    __builtin_amdgcn_global_load_lds(
        (const __attribute__((address_space(1))) void*)g1,
        (__attribute__((address_space(3))) void*)l1, 16, 0, 0);
}

__device__ __forceinline__ void stage64x32(const u16* g, int ld, u16* lds, int tid) {
    const int w = tid >> 6;
    const int l = tid & 63;
    const int r = w * 16 + (l >> 2);
    const int c = (l & 3) * 8;
    const u16* g0 = g + (size_t)r * ld + c;
    u16* l0 = lds + w * 16 * LDK;
    __builtin_amdgcn_global_load_lds(
        (const __attribute__((address_space(1))) void*)g0,
        (__attribute__((address_space(3))) void*)l0, 16, 0, 0);
}

// Bijective XCD-aware block swizzle (requires gridDim.x*gridDim.y % 8 == 0).
// Consecutive by-rows land on the same XCD L2 so the shared A-panel is
// fetched once per XCD, not 8x.
__device__ __forceinline__ void xcd_swz(int& bx, int& by) {
    const int nx  = gridDim.x;
    const int nwg = nx * gridDim.y;
    const int lid = blockIdx.y * nx + blockIdx.x;
    const int q   = nwg >> 3;
    const int s   = (lid & 7) * q + (lid >> 3);
    bx = s % nx;
    by = s / nx;
}

// ---------------------------------------------------------------------------
// Fold batch: 6 spectral layers, z-indexed kernels (3 launches total).
// Mt[s][o][j] = sc * sum_m fw[m][o] * w[(m-j) mod n]
// ---------------------------------------------------------------------------
struct FoldBatch {
    const float* w[6];
    const float* fw[6];
    u16* t1[6];    // fwT bf16: t1[o][m] = bf16(fw[m][o])
    u16* t2[6];    // circ bf16: t2[j][m] = bf16(w[(m-j) mod n])
    u16* mt[6];    // output Mt bf16 [n][n]
    int  n[6], lg[6];
    float sc[6];
};

__global__ __launch_bounds__(256) void fold_trconv(FoldBatch fb) {
    const int z = blockIdx.z;
    const int n = fb.n[z];
    const int bx = blockIdx.x * 32, by = blockIdx.y * 32;
    if (bx >= n || by >= n) return;
    __shared__ float t[32][33];
    const int tx = threadIdx.x & 31, ty = threadIdx.x >> 5;   // 32x8
    const float* src = fb.fw[z];
    u16* dst = fb.t1[z];
#pragma unroll
    for (int r = 0; r < 32; r += 8)
        t[ty + r][tx] = src[(size_t)(by + ty + r) * n + bx + tx];
    __syncthreads();
#pragma unroll
    for (int r = 0; r < 32; r += 8)
        dst[(size_t)(bx + ty + r) * n + by + tx] = f2bu(t[tx][ty + r]);
}

__global__ __launch_bounds__(256) void fold_circ(FoldBatch fb) {
    const int z = blockIdx.z;
    const int n = fb.n[z], lg = fb.lg[z];
    int idx = blockIdx.x * 256 + threadIdx.x;
    if (idx >= n * n) return;
    int mask = n - 1;
    int m = idx & mask;
    int j = idx >> lg;
    fb.t2[z][idx] = f2bu(fb.w[z][(m - j) & mask]);
}

__global__ __launch_bounds__(256) void fold_gemm(FoldBatch fb) {
    const int z = blockIdx.z;
    const int n = fb.n[z];
    const int bm = blockIdx.y * 128, bn = blockIdx.x * 128;
    if (bm >= n || bn >= n) return;
    const u16* A  = fb.t1[z];
    const u16* Bt = fb.t2[z];
    u16* Mt = fb.mt[z];
    const float scale = fb.sc[z];

    __shared__ u16 Asl[2][128 * LDK];
    __shared__ u16 Bsl[2][128 * LDK];
    const int tid = threadIdx.x;
    const int lane = tid & 63, wave = tid >> 6;
    const int wy = wave >> 1, wx = wave & 1;
    const int qd = lane >> 4, ln16 = lane & 15;

    f32x4 acc[4][4];
#pragma unroll
    for (int i = 0; i < 4; i++)
#pragma unroll
        for (int j = 0; j < 4; j++)
#pragma unroll
            for (int r = 0; r < 4; r++) acc[i][j][r] = 0.f;

    const u16* Ab = A  + (size_t)bm * n;
    const u16* Bb = Bt + (size_t)bn * n;
    stage128x32(Ab, n, Asl[0], tid);
    stage128x32(Bb, n, Bsl[0], tid);
    __syncthreads();
    int cur = 0;
    for (int k0 = 0; k0 < n; k0 += 32) {
        if (k0 + 32 < n) {                       // prefetch next tile (async)
            stage128x32(Ab + k0 + 32, n, Asl[cur ^ 1], tid);
            stage128x32(Bb + k0 + 32, n, Bsl[cur ^ 1], tid);
        }
        const u16* Ac = Asl[cur];
        const u16* Bc = Bsl[cur];
        short8 af[4], bf_[4];
#pragma unroll
        for (int i = 0; i < 4; i++) {
            af[i]  = *(const short8*)&Ac[(wy * 64 + i * 16 + ln16) * LDK + qd * 8];
            bf_[i] = *(const short8*)&Bc[(wx * 64 + i * 16 + ln16) * LDK + qd * 8];
        }
#pragma unroll
        for (int i = 0; i < 4; i++)
#pragma unroll
            for (int j = 0; j < 4; j++)
                acc[i][j] = __builtin_amdgcn_mfma_f32_16x16x32_bf16(af[i], bf_[j], acc[i][j], 0, 0, 0);
        __syncthreads();                         // drains prefetch + guards swap
        cur ^= 1;
    }
#pragma unroll
    for (int i = 0; i < 4; i++)
#pragma unroll
        for (int j = 0; j < 4; j++) {
            const int col = bn + wx * 64 + j * 16 + ln16;
#pragma unroll
            for (int r = 0; r < 4; r++) {
                const int row = bm + wy * 64 + i * 16 + qd * 4 + r;
                Mt[(size_t)row * n + col] = f2bu(acc[i][j][r] * scale);
            }
        }
}

// ---------------------------------------------------------------------------
// bf16 MFMA GEMM (single B): C = act( A @ B + bias ). B pre-transposed.
// 128x64 tile (BN=64 for occupancy), BK=32, 4 waves (2x2), dbuf prefetch,
// 1 barrier/iter. mode: 0 none, 1 gelu(exact).
// Optional outputs: Cf fp32, Cb bf16(v), Cb2 bf16(aux - v).
// ---------------------------------------------------------------------------
__global__ __launch_bounds__(256) void gemm_bf(
    const u16* __restrict__ A, int lda,
    const u16* __restrict__ Bt, int ldb,
    const float* __restrict__ bias,
    float* __restrict__ Cf, int ldc,
    u16* __restrict__ Cb, int ldcb,
    u16* __restrict__ Cb2, int ldcb2,
    const float* __restrict__ aux, int ldaux,
    int K, int mode)
{
    __shared__ u16 Asl[2][128 * LDK];
    __shared__ u16 Bsl[2][64 * LDK];
    const int tid = threadIdx.x;
    int bxs, bys;
    xcd_swz(bxs, bys);
    const int bm = bys * 128, bn = bxs * 64;
    const int lane = tid & 63, wave = tid >> 6;
    const int wy = wave >> 1, wx = wave & 1;
    const int qd = lane >> 4, ln16 = lane & 15;

    f32x4 acc[4][2];
#pragma unroll
    for (int i = 0; i < 4; i++)
#pragma unroll
        for (int j = 0; j < 2; j++)
#pragma unroll
            for (int r = 0; r < 4; r++) acc[i][j][r] = 0.f;

    const u16* Ab = A  + (size_t)bm * lda;
    const u16* Bb = Bt + (size_t)bn * ldb;
    stage128x32(Ab, lda, Asl[0], tid);
    stage64x32(Bb, ldb, Bsl[0], tid);
    __syncthreads();
    int cur = 0;
    for (int k0 = 0; k0 < K; k0 += 32) {
        if (k0 + 32 < K) {
            stage128x32(Ab + k0 + 32, lda, Asl[cur ^ 1], tid);
            stage64x32(Bb + k0 + 32, ldb, Bsl[cur ^ 1], tid);
        }
        const u16* Ac = Asl[cur];
        const u16* Bc = Bsl[cur];
        short8 af[4], bf_[2];
#pragma unroll
        for (int i = 0; i < 4; i++)
            af[i]  = *(const short8*)&Ac[(wy * 64 + i * 16 + ln16) * LDK + qd * 8];
#pragma unroll
        for (int j = 0; j < 2; j++)
            bf_[j] = *(const short8*)&Bc[(wx * 32 + j * 16 + ln16) * LDK + qd * 8];
#pragma unroll
        for (int i = 0; i < 4; i++)
#pragma unroll
            for (int j = 0; j < 2; j++)
                acc[i][j] = __builtin_amdgcn_mfma_f32_16x16x32_bf16(af[i], bf_[j], acc[i][j], 0, 0, 0);
        __syncthreads();
        cur ^= 1;
    }

#pragma unroll
    for (int i = 0; i < 4; i++) {
#pragma unroll
        for (int j = 0; j < 2; j++) {
            const int col = bn + wx * 32 + j * 16 + ln16;
            const float b_ = bias ? bias[col] : 0.f;
#pragma unroll
            for (int r = 0; r < 4; r++) {
                const int row = bm + wy * 64 + i * 16 + qd * 4 + r;
                float v = acc[i][j][r] + b_;
                if (mode == 1) v = 0.5f * v * (1.0f + erff(v * 0.7071067811865476f));
                if (Cf)  Cf[(size_t)row * ldc + col] = v;
                if (Cb)  Cb[(size_t)row * ldcb + col] = f2bu(v);
                if (Cb2) Cb2[(size_t)row * ldcb2 + col] =
                             f2bu(aux[(size_t)row * ldaux + col] - v);
            }
        }
    }
}

// ---------------------------------------------------------------------------
// Dual-B fused gate GEMM: C = sigmoid(A@B1 + b1) * (A@B2 + b2), fp32 out.
// 128x64 tile, A staged once, 16 MFMA/iter/wave, dbuf prefetch.
// ---------------------------------------------------------------------------
__global__ __launch_bounds__(256) void gemm_bf2(
    const u16* __restrict__ A, int lda,
    const u16* __restrict__ B1t, const u16* __restrict__ B2t, int ldb,
    const float* __restrict__ bias1, const float* __restrict__ bias2,
    float* __restrict__ Cf, int ldc, int K)
{
    __shared__ u16 Asl[2][128 * LDK];
    __shared__ u16 B1sl[2][64 * LDK];
    __shared__ u16 B2sl[2][64 * LDK];
    const int tid = threadIdx.x;
    int bxs, bys;
    xcd_swz(bxs, bys);
    const int bm = bys * 128, bn = bxs * 64;
    const int lane = tid & 63, wave = tid >> 6;
    const int wy = wave >> 1, wx = wave & 1;
    const int qd = lane >> 4, ln16 = lane & 15;

    f32x4 acc1[4][2], acc2[4][2];
#pragma unroll
    for (int i = 0; i < 4; i++)
#pragma unroll
        for (int j = 0; j < 2; j++)
#pragma unroll
            for (int r = 0; r < 4; r++) { acc1[i][j][r] = 0.f; acc2[i][j][r] = 0.f; }

    const u16* Ab  = A   + (size_t)bm * lda;
    const u16* B1b = B1t + (size_t)bn * ldb;
    const u16* B2b = B2t + (size_t)bn * ldb;
    stage128x32(Ab,  lda, Asl[0],  tid);
    stage64x32(B1b, ldb, B1sl[0], tid);
    stage64x32(B2b, ldb, B2sl[0], tid);
    __syncthreads();
    int cur = 0;
    for (int k0 = 0; k0 < K; k0 += 32) {
        if (k0 + 32 < K) {
            stage128x32(Ab  + k0 + 32, lda, Asl[cur ^ 1],  tid);
            stage64x32(B1b + k0 + 32, ldb, B1sl[cur ^ 1], tid);
            stage64x32(B2b + k0 + 32, ldb, B2sl[cur ^ 1], tid);
        }
        const u16* Ac  = Asl[cur];
        const u16* B1c = B1sl[cur];
        const u16* B2c = B2sl[cur];
        short8 af[4], b1f[2], b2f[2];
#pragma unroll
        for (int i = 0; i < 4; i++)
            af[i]  = *(const short8*)&Ac [(wy * 64 + i * 16 + ln16) * LDK + qd * 8];
#pragma unroll
        for (int j = 0; j < 2; j++) {
            b1f[j] = *(const short8*)&B1c[(wx * 32 + j * 16 + ln16) * LDK + qd * 8];
            b2f[j] = *(const short8*)&B2c[(wx * 32 + j * 16 + ln16) * LDK + qd * 8];
        }
#pragma unroll
        for (int i = 0; i < 4; i++)
#pragma unroll
            for (int j = 0; j < 2; j++) {
                acc1[i][j] = __builtin_amdgcn_mfma_f32_16x16x32_bf16(af[i], b1f[j], acc1[i][j], 0, 0, 0);
                acc2[i][j] = __builtin_amdgcn_mfma_f32_16x16x32_bf16(af[i], b2f[j], acc2[i][j], 0, 0, 0);
            }
        __syncthreads();
        cur ^= 1;
    }

#pragma unroll
    for (int i = 0; i < 4; i++) {
#pragma unroll
        for (int j = 0; j < 2; j++) {
            const int col = bn + wx * 32 + j * 16 + ln16;
            const float b1_ = bias1[col], b2_ = bias2[col];
#pragma unroll
            for (int r = 0; r < 4; r++) {
                const int row = bm + wy * 64 + i * 16 + qd * 4 + r;
                const float g = 1.0f / (1.0f + expf(-(acc1[i][j][r] + b1_)));
                Cf[(size_t)row * ldc + col] = g * (acc2[i][j][r] + b2_);
            }
        }
    }
}

// ---------------------------------------------------------------------------
// LayerNorm over 512 features. in1b optional bf16 add. fp32 + optional bf16 out.
// ---------------------------------------------------------------------------
__global__ __launch_bounds__(256) void ln_kernel(
    const float* __restrict__ in0, int ld0,
    const u16* __restrict__ in1b, int ld1b,
    const float* __restrict__ g, const float* __restrict__ bta,
    float* __restrict__ outf, int ldo,
    u16* __restrict__ outb, int ldob)
{
    int row = blockIdx.x, tid = threadIdx.x;
    const float* p0 = in0 + (size_t)row * ld0;
    float v0 = p0[tid], v1 = p0[tid + 256];
    if (in1b) {
        const u16* p1 = in1b + (size_t)row * ld1b;
        union { unsigned u; float f; } c0, c1;
        c0.u = ((unsigned)p1[tid]) << 16;
        c1.u = ((unsigned)p1[tid + 256]) << 16;
        v0 += c0.f; v1 += c1.f;
    }
    float s = v0 + v1, sq = v0 * v0 + v1 * v1;
#pragma unroll
    for (int o = 32; o > 0; o >>= 1) {
        s  += __shfl_xor(s, o);
        sq += __shfl_xor(sq, o);
    }
    __shared__ float red[8];
    int wid = tid >> 6;
    if ((tid & 63) == 0) { red[wid] = s; red[4 + wid] = sq; }
    __syncthreads();
    s  = red[0] + red[1] + red[2] + red[3];
    sq = red[4] + red[5] + red[6] + red[7];
    float mean = s * (1.0f / 512.0f);
    float var  = sq * (1.0f / 512.0f) - mean * mean;
    float rstd = rsqrtf(var + 1e-5f);
    float o0 = (v0 - mean) * rstd * g[tid] + bta[tid];
    float o1 = (v1 - mean) * rstd * g[tid + 256] + bta[tid + 256];
    if (outf) {
        outf[(size_t)row * ldo + tid]       = o0;
        outf[(size_t)row * ldo + tid + 256] = o1;
    }
    if (outb) {
        outb[(size_t)row * ldob + tid]       = f2bu(o0);
        outb[(size_t)row * ldob + tid + 256] = f2bu(o1);
    }
}

// ---------------------------------------------------------------------------
// MFMA flash attention, q==k==v bf16, head_dim 64. exp2-domain softmax.
// Writes bf16 new_x into catb[:, 0:512] (ld 1024).
// ---------------------------------------------------------------------------
#define AP 72   /* LDS pitch in bf16 elems */

__global__ __launch_bounds__(256) void attn_mfma(const u16* __restrict__ qall,
                                                 u16* __restrict__ catb) {
    __shared__ u16 Ks[64 * AP];        // [key][d]
    __shared__ u16 KsT[64 * AP];       // [d][key]
    __shared__ u16 Pw[4][16 * AP];     // per-wave P [row][key]

    const int bid = blockIdx.x;
    const int lt = bid & 15, hh = (bid >> 4) & 7, bb = bid >> 7;
    const int q0 = lt * 64;
    const int tid = threadIdx.x;
    const int wave = tid >> 6, lane = tid & 63;
    const int quad = lane >> 4, ln16 = lane & 15;

    const u16* qh = qall + (size_t)bb * SEQ * EDIM + hh * 64;

    const u16* qrow = qh + (size_t)(q0 + wave * 16 + ln16) * EDIM + quad * 8;
    const short8 aq0 = *(const short8*)(qrow);
    const short8 aq1 = *(const short8*)(qrow + 32);

    f32x4 oacc[4];
    float m_run[4], l_run[4];
#pragma unroll
    for (int j = 0; j < 4; j++)
#pragma unroll
        for (int r = 0; r < 4; r++) oacc[j][r] = 0.f;
#pragma unroll
    for (int r = 0; r < 4; r++) { m_run[r] = -1e30f; l_run[r] = 0.f; }

    const int sr  = tid & 63;
    const int scq = (tid >> 6) * 16;

    for (int s0 = 0; s0 < SEQ; s0 += 64) {
        __syncthreads();
        {
            const u16* krow = qh + (size_t)(s0 + sr) * EDIM + scq;
            uint4 v0 = *(const uint4*)(krow);
            uint4 v1 = *(const uint4*)(krow + 8);
            *(uint4*)&Ks[sr * AP + scq]     = v0;
            *(uint4*)&Ks[sr * AP + scq + 8] = v1;
            const u16* h0 = (const u16*)&v0;
            const u16* h1 = (const u16*)&v1;
#pragma unroll
            for (int i = 0; i < 8; i++) KsT[(scq + i) * AP + sr]     = h0[i];
#pragma unroll
            for (int i = 0; i < 8; i++) KsT[(scq + 8 + i) * AP + sr] = h1[i];
        }
        __syncthreads();

        f32x4 S[4];
#pragma unroll
        for (int j = 0; j < 4; j++) {
            const int krw = (j * 16 + ln16) * AP + quad * 8;
            short8 b0 = *(const short8*)&Ks[krw];
            short8 b1 = *(const short8*)&Ks[krw + 32];
            f32x4 c = {0.f, 0.f, 0.f, 0.f};
            c = __builtin_amdgcn_mfma_f32_16x16x32_bf16(aq0, b0, c, 0, 0, 0);
            c = __builtin_amdgcn_mfma_f32_16x16x32_bf16(aq1, b1, c, 0, 0, 0);
            S[j] = c;
        }

#pragma unroll
        for (int r = 0; r < 4; r++) {
            float v0_ = S[0][r] * ATT_SCL;       // log2-domain scores
            float v1_ = S[1][r] * ATT_SCL;
            float v2_ = S[2][r] * ATT_SCL;
            float v3_ = S[3][r] * ATT_SCL;
            float mx = fmaxf(fmaxf(v0_, v1_), fmaxf(v2_, v3_));
            mx = fmaxf(mx, __shfl_xor(mx, 1));
            mx = fmaxf(mx, __shfl_xor(mx, 2));
            mx = fmaxf(mx, __shfl_xor(mx, 4));
            mx = fmaxf(mx, __shfl_xor(mx, 8));
            float mn = fmaxf(m_run[r], mx);
            float al = exp2f(m_run[r] - mn);
            m_run[r] = mn;
            float p0 = exp2f(v0_ - mn), p1 = exp2f(v1_ - mn);
            float p2 = exp2f(v2_ - mn), p3 = exp2f(v3_ - mn);
            float rs = p0 + p1 + p2 + p3;
            rs += __shfl_xor(rs, 1); rs += __shfl_xor(rs, 2);
            rs += __shfl_xor(rs, 4); rs += __shfl_xor(rs, 8);
            l_run[r] = l_run[r] * al + rs;
            oacc[0][r] *= al; oacc[1][r] *= al;
            oacc[2][r] *= al; oacc[3][r] *= al;
            const int pb = (quad * 4 + r) * AP + ln16;
            Pw[wave][pb]      = f2bu(p0);
            Pw[wave][pb + 16] = f2bu(p1);
            Pw[wave][pb + 32] = f2bu(p2);
            Pw[wave][pb + 48] = f2bu(p3);
        }

        short8 pa0 = *(const short8*)&Pw[wave][ln16 * AP + quad * 8];
        short8 pa1 = *(const short8*)&Pw[wave][ln16 * AP + 32 + quad * 8];

#pragma unroll
        for (int j = 0; j < 4; j++) {
            const int drw = (j * 16 + ln16) * AP + quad * 8;
            short8 b0 = *(const short8*)&KsT[drw];
            short8 b1 = *(const short8*)&KsT[drw + 32];
            oacc[j] = __builtin_amdgcn_mfma_f32_16x16x32_bf16(pa0, b0, oacc[j], 0, 0, 0);
            oacc[j] = __builtin_amdgcn_mfma_f32_16x16x32_bf16(pa1, b1, oacc[j], 0, 0, 0);
        }
    }

#pragma unroll
    for (int r = 0; r < 4; r++) {
        const float inv = 1.0f / l_run[r];
        const int row = bb * SEQ + q0 + wave * 16 + quad * 4 + r;
#pragma unroll
        for (int j = 0; j < 4; j++) {
            const int col = hh * 64 + j * 16 + ln16;
            catb[(size_t)row * E2DIM + col] = f2bu(oacc[j][r] * inv);
        }
    }
}

// ---------------------------------------------------------------------------
// Host launch
// ---------------------------------------------------------------------------
extern "C" void kernel_launch(void* const* d_in, const int* in_sizes, int n_in,
                              void* d_out, int out_size, void* d_ws, size_t ws_size,
                              hipStream_t stream)
{
    // ---- workspace layout (float units) ----
    const size_t OFF_MT0 = 0;
    const size_t OFF_MT1 = OFF_MT0 + 131072;
    const size_t OFF_MT2 = OFF_MT1 + 131072;
    const size_t OFF_MT3 = OFF_MT2 + 131072;
    const size_t OFF_MT4 = OFF_MT3 + 131072;
    const size_t OFF_MT5 = OFF_MT4 + 524288;
    const size_t OFF_XB  = OFF_MT5 + 524288;        // x_bf / x1_bf (bf16 8192x512)
    const size_t OFF_CB  = OFF_XB + 2097152;        // cat bf16 [8192,1024]
    const size_t OFF_BQ  = OFF_CB + 4194304;        // q bf16 -> x2 bf16
    const size_t OFF_BN  = OFF_BQ + 4194304;        // fold t1 scratch -> h fp32
    const size_t OFF_BC  = OFF_BN + 4194304;        // fold t2 scratch -> x1 fp32
    const size_t OFF_P   = OFF_BC + 4194304;        // fp32-converted inputs

    float* W = (float*)d_ws;
    u16* MT[6] = {(u16*)(W + OFF_MT0), (u16*)(W + OFF_MT1), (u16*)(W + OFF_MT2),
                  (u16*)(W + OFF_MT3), (u16*)(W + OFF_MT4), (u16*)(W + OFF_MT5)};
    u16*   XB  = (u16*)(W + OFF_XB);
    u16*   CB  = (u16*)(W + OFF_CB);
    u16*   QB  = (u16*)(W + OFF_BQ);   // q bf16; later x2 bf16 (sequential reuse)
    float* BN  = W + OFF_BN;           // h fp32 (after fold)
    float* BC  = W + OFF_BC;           // x1 fp32 (after fold)

    float* F[23];
    CvtBatch cb;
    int pre = 0;
    for (int i = 0; i < 23 && i < n_in; i++) {
        cb.pre4[i] = pre;
        F[i] = W + OFF_P + (size_t)pre * 4;
        cb.src[i] = d_in[i];
        cb.dst[i] = (float4*)F[i];
        pre += in_sizes[i] / 4;
    }
    cb.pre4[23] = pre;
    const int total4 = pre;
    int* FLAG = (int*)(W + OFF_P + (size_t)total4 * 4);

    if (n_in < 23) return;
    if (ws_size < (OFF_P + (size_t)total4 * 4 + 16) * sizeof(float)) return;

    detect_dtype<<<1, 256, 0, stream>>>((const u16*)d_in[0], FLAG);
    cvt_all<<<(total4 + 255) / 256, 256, 0, stream>>>(cb, total4, FLAG);
    f2b_kernel<<<(ROWS * EDIM / 4 + 255) / 256, 256, 0, stream>>>(F[0], XB, ROWS * EDIM / 4);

    // ---- fold (3 batched launches): scratch overlays BN/BC (dead here) ----
    FoldBatch fb;
    {
        const int wi[6] = {1, 4, 7, 10, 13, 16};
        u16* T1 = (u16*)BN;
        u16* T2 = (u16*)BC;
        size_t off = 0;
        for (int s = 0; s < 6; s++) {
            const int n = (s < 4) ? 512 : 1024;
            fb.w[s]  = F[wi[s]];
            fb.fw[s] = F[wi[s] + 1];
            fb.t1[s] = T1 + off;
            fb.t2[s] = T2 + off;
            fb.mt[s] = MT[s];
            fb.n[s]  = n;
            fb.lg[s] = (s < 4) ? 9 : 10;
            fb.sc[s] = (s < 4) ? 0.04419417382415922f : 0.03125f;
            off += (size_t)n * n;
        }
    }
    fold_trconv<<<dim3(32, 32, 6), 256, 0, stream>>>(fb);
    fold_circ<<<dim3(4096, 1, 6), 256, 0, stream>>>(fb);
    fold_gemm<<<dim3(8, 8, 6), 256, 0, stream>>>(fb);

    float* out0 = (float*)d_out;                       // LN(h): [8192,512]
    float* out1 = (float*)d_out + (size_t)ROWS * EDIM; // out:   [8192,1024]

    // q = x @ M0 + attn_fb                                  -> QB (bf16)
    gemm_bf<<<dim3(8, 64), 256, 0, stream>>>(
        XB, 512, MT[0], 512, F[3], nullptr, 0, QB, 512, nullptr, 0, nullptr, 0, 512, 0);
    // attention -> cat bf16 [:, :512]
    attn_mfma<<<1024, 256, 0, stream>>>(QB, CB);
    // x1 = LN(x + newx; n1)                                 -> BC fp32 + XB bf16
    ln_kernel<<<8192, 256, 0, stream>>>(F[0], 512, CB, 1024, F[19], F[20],
                                        BC, 512, XB, 512);
    // x_ln = gelu(x1 @ M1 + b); cat[:,512:]=bf16(v); x2=bf16(x1-v) -> QB
    gemm_bf<<<dim3(8, 64), 256, 0, stream>>>(
        XB, 512, MT[1], 512, F[6], nullptr, 0, CB + 512, 1024, QB, 512, BC, 512, 512, 1);
    // h = sigmoid(x2@M2+b2) * (x2@M3+b3)                     -> BN fp32
    gemm_bf2<<<dim3(8, 64), 256, 0, stream>>>(
        QB, 512, MT[2], MT[3], 512, F[9], F[12], BN, 512, 512);
    // out0 = LN(h; n2)                                       -> d_out
    ln_kernel<<<8192, 256, 0, stream>>>(BN, 512, nullptr, 0, F[21], F[22],
                                        out0, 512, nullptr, 0);
    // out1 = sigmoid(cat@M4+b4) * (cat@M5+b5)                -> d_out+4M
    gemm_bf2<<<dim3(16, 64), 256, 0, stream>>>(
        CB, 1024, MT[4], MT[5], 1024, F[15], F[18], out1, 1024, 1024);
}

// Round 4
// 348.354 us; speedup vs baseline: 1.3140x; 1.0660x over previous
//
#include <hip/hip_runtime.h>
#include <hip/hip_bf16.h>
#include <math.h>

typedef __hip_bfloat16 bf16;
typedef unsigned short u16;
typedef __attribute__((ext_vector_type(8))) short short8;
typedef __attribute__((ext_vector_type(4))) float f32x4;

#define NB      8
#define SEQ     1024
#define EDIM    512
#define E2DIM   1024
#define ROWS    8192
#define INV_SQRT_E 0.04419417382415922f
#define ATT_SCL    0.06375985678148161f   /* INV_SQRT_E * log2(e) */

__device__ inline u16 f2bu(float f) {           // fp32 -> bf16 bits, RNE
    union { float f; unsigned u; } c; c.f = f;
    return (u16)((c.u + 0x7FFF + ((c.u >> 16) & 1)) >> 16);
}

__device__ __forceinline__ unsigned cvtpk_bf16(float lo, float hi) {
    unsigned r;
    asm("v_cvt_pk_bf16_f32 %0, %1, %2" : "=v"(r) : "v"(lo), "v"(hi));
    return r;
}

// ---------------------------------------------------------------------------
// Input dtype autodetect (proved inputs are fp32; kept as cheap insurance).
// ---------------------------------------------------------------------------
__global__ __launch_bounds__(256) void detect_dtype(const u16* __restrict__ x,
                                                    int* __restrict__ flag) {
    int t = threadIdx.x;
    int cnt = 0;
    for (int k = t; k < 8192; k += 256) {
        int e = (x[k] >> 7) & 0xFF;
        if (e >= 0xC0) cnt++;
    }
#pragma unroll
    for (int o = 32; o > 0; o >>= 1) cnt += __shfl_xor(cnt, o);
    __shared__ int red[4];
    if ((t & 63) == 0) red[t >> 6] = cnt;
    __syncthreads();
    if (t == 0) flag[0] = (red[0] + red[1] + red[2] + red[3] > 100) ? 1 : 0;
}

// ---------------------------------------------------------------------------
// Batch conversion of all 23 inputs -> fp32 workspace (dtype-adaptive).
// ---------------------------------------------------------------------------
struct CvtBatch {
    const void* src[23];
    float4*     dst[23];
    int         pre4[24];
};

__global__ __launch_bounds__(256) void cvt_all(CvtBatch a, int total4,
                                               const int* __restrict__ flag) {
    int t = blockIdx.x * 256 + threadIdx.x;
    if (t >= total4) return;
    int lo = 0;
    while (t >= a.pre4[lo + 1]) lo++;
    int li = t - a.pre4[lo];
    if (flag[0]) {
        a.dst[lo][li] = ((const float4*)a.src[lo])[li];
    } else {
        ushort4 u = ((const ushort4*)a.src[lo])[li];
        union { unsigned int i; float f; } c;
        float4 o;
        c.i = ((unsigned)u.x) << 16; o.x = c.f;
        c.i = ((unsigned)u.y) << 16; o.y = c.f;
        c.i = ((unsigned)u.z) << 16; o.z = c.f;
        c.i = ((unsigned)u.w) << 16; o.w = c.f;
        a.dst[lo][li] = o;
    }
}

// fp32 -> bf16 elementwise, n/4 threads
__global__ __launch_bounds__(256) void f2b_kernel(const float* __restrict__ src,
                                                  u16* __restrict__ dst, int n4) {
    int i = blockIdx.x * 256 + threadIdx.x;
    if (i >= n4) return;
    float4 a = ((const float4*)src)[i];
    ushort4 o;
    o.x = f2bu(a.x); o.y = f2bu(a.y); o.z = f2bu(a.z); o.w = f2bu(a.w);
    ((ushort4*)dst)[i] = o;
}

// ---------------------------------------------------------------------------
// async global->LDS staging (linear LDS, width=16).
// LDS dest is wave-uniform base + lane*16 (HW rule); global src is per-lane.
// ---------------------------------------------------------------------------
#define LDK 32   /* linear LDS row: 32 bf16 = 64 B */

__device__ __forceinline__ void stage128x32(const u16* g, int ld, u16* lds, int tid) {
    const int w = tid >> 6;              // wave id (uniform within wave)
    const int l = tid & 63;
    const int r = w * 16 + (l >> 2);     // row covered by this lane
    const int c = (l & 3) * 8;           // 16B chunk within row
    const u16* g0 = g + (size_t)r * ld + c;
    u16* l0 = lds + w * 16 * LDK;        // wave-uniform LDS base
    __builtin_amdgcn_global_load_lds(
        (const __attribute__((address_space(1))) void*)g0,
        (__attribute__((address_space(3))) void*)l0, 16, 0, 0);
    const u16* g1 = g0 + (size_t)64 * ld;
    u16* l1 = l0 + 64 * LDK;
    __builtin_amdgcn_global_load_lds(
        (const __attribute__((address_space(1))) void*)g1,
        (__attribute__((address_space(3))) void*)l1, 16, 0, 0);
}

__device__ __forceinline__ void stage64x32(const u16* g, int ld, u16* lds, int tid) {
    const int w = tid >> 6;
    const int l = tid & 63;
    const int r = w * 16 + (l >> 2);
    const int c = (l & 3) * 8;
    const u16* g0 = g + (size_t)r * ld + c;
    u16* l0 = lds + w * 16 * LDK;
    __builtin_amdgcn_global_load_lds(
        (const __attribute__((address_space(1))) void*)g0,
        (__attribute__((address_space(3))) void*)l0, 16, 0, 0);
}

// Bijective XCD-aware block swizzle (requires gridDim.x*gridDim.y % 8 == 0).
// Consecutive by-rows land on the same XCD L2 so the shared A-panel is
// fetched once per XCD, not 8x.
__device__ __forceinline__ void xcd_swz(int& bx, int& by) {
    const int nx  = gridDim.x;
    const int nwg = nx * gridDim.y;
    const int lid = blockIdx.y * nx + blockIdx.x;
    const int q   = nwg >> 3;
    const int s   = (lid & 7) * q + (lid >> 3);
    bx = s % nx;
    by = s / nx;
}

// ---------------------------------------------------------------------------
// Fold batch: 6 spectral layers, z-indexed kernels (3 launches total).
// Mt[s][o][j] = sc * sum_m fw[m][o] * w[(m-j) mod n]
// ---------------------------------------------------------------------------
struct FoldBatch {
    const float* w[6];
    const float* fw[6];
    u16* t1[6];    // fwT bf16: t1[o][m] = bf16(fw[m][o])
    u16* t2[6];    // circ bf16: t2[j][m] = bf16(w[(m-j) mod n])
    u16* mt[6];    // output Mt bf16 [n][n]
    int  n[6], lg[6];
    float sc[6];
};

__global__ __launch_bounds__(256) void fold_trconv(FoldBatch fb) {
    const int z = blockIdx.z;
    const int n = fb.n[z];
    const int bx = blockIdx.x * 32, by = blockIdx.y * 32;
    if (bx >= n || by >= n) return;
    __shared__ float t[32][33];
    const int tx = threadIdx.x & 31, ty = threadIdx.x >> 5;   // 32x8
    const float* src = fb.fw[z];
    u16* dst = fb.t1[z];
#pragma unroll
    for (int r = 0; r < 32; r += 8)
        t[ty + r][tx] = src[(size_t)(by + ty + r) * n + bx + tx];
    __syncthreads();
#pragma unroll
    for (int r = 0; r < 32; r += 8)
        dst[(size_t)(bx + ty + r) * n + by + tx] = f2bu(t[tx][ty + r]);
}

__global__ __launch_bounds__(256) void fold_circ(FoldBatch fb) {
    const int z = blockIdx.z;
    const int n = fb.n[z], lg = fb.lg[z];
    int idx = blockIdx.x * 256 + threadIdx.x;
    if (idx >= n * n) return;
    int mask = n - 1;
    int m = idx & mask;
    int j = idx >> lg;
    fb.t2[z][idx] = f2bu(fb.w[z][(m - j) & mask]);
}

__global__ __launch_bounds__(256) void fold_gemm(FoldBatch fb) {
    const int z = blockIdx.z;
    const int n = fb.n[z];
    const int bm = blockIdx.y * 128, bn = blockIdx.x * 128;
    if (bm >= n || bn >= n) return;
    const u16* A  = fb.t1[z];
    const u16* Bt = fb.t2[z];
    u16* Mt = fb.mt[z];
    const float scale = fb.sc[z];

    __shared__ u16 Asl[2][128 * LDK];
    __shared__ u16 Bsl[2][128 * LDK];
    const int tid = threadIdx.x;
    const int lane = tid & 63, wave = tid >> 6;
    const int wy = wave >> 1, wx = wave & 1;
    const int qd = lane >> 4, ln16 = lane & 15;

    f32x4 acc[4][4];
#pragma unroll
    for (int i = 0; i < 4; i++)
#pragma unroll
        for (int j = 0; j < 4; j++)
#pragma unroll
            for (int r = 0; r < 4; r++) acc[i][j][r] = 0.f;

    const u16* Ab = A  + (size_t)bm * n;
    const u16* Bb = Bt + (size_t)bn * n;
    stage128x32(Ab, n, Asl[0], tid);
    stage128x32(Bb, n, Bsl[0], tid);
    __syncthreads();
    int cur = 0;
    for (int k0 = 0; k0 < n; k0 += 32) {
        if (k0 + 32 < n) {                       // prefetch next tile (async)
            stage128x32(Ab + k0 + 32, n, Asl[cur ^ 1], tid);
            stage128x32(Bb + k0 + 32, n, Bsl[cur ^ 1], tid);
        }
        const u16* Ac = Asl[cur];
        const u16* Bc = Bsl[cur];
        short8 af[4], bf_[4];
#pragma unroll
        for (int i = 0; i < 4; i++) {
            af[i]  = *(const short8*)&Ac[(wy * 64 + i * 16 + ln16) * LDK + qd * 8];
            bf_[i] = *(const short8*)&Bc[(wx * 64 + i * 16 + ln16) * LDK + qd * 8];
        }
#pragma unroll
        for (int i = 0; i < 4; i++)
#pragma unroll
            for (int j = 0; j < 4; j++)
                acc[i][j] = __builtin_amdgcn_mfma_f32_16x16x32_bf16(af[i], bf_[j], acc[i][j], 0, 0, 0);
        __syncthreads();                         // drains prefetch + guards swap
        cur ^= 1;
    }
#pragma unroll
    for (int i = 0; i < 4; i++)
#pragma unroll
        for (int j = 0; j < 4; j++) {
            const int col = bn + wx * 64 + j * 16 + ln16;
#pragma unroll
            for (int r = 0; r < 4; r++) {
                const int row = bm + wy * 64 + i * 16 + qd * 4 + r;
                Mt[(size_t)row * n + col] = f2bu(acc[i][j][r] * scale);
            }
        }
}

// ---------------------------------------------------------------------------
// bf16 MFMA GEMM (single B): C = act( A @ B + bias ). B pre-transposed.
// 128x64 tile (BN=64 for occupancy), BK=32, 4 waves (2x2), dbuf prefetch,
// 1 barrier/iter. mode: 0 none, 1 gelu(exact).
// Optional outputs: Cf fp32, Cb bf16(v), Cb2 bf16(aux - v).
// ---------------------------------------------------------------------------
__global__ __launch_bounds__(256) void gemm_bf(
    const u16* __restrict__ A, int lda,
    const u16* __restrict__ Bt, int ldb,
    const float* __restrict__ bias,
    float* __restrict__ Cf, int ldc,
    u16* __restrict__ Cb, int ldcb,
    u16* __restrict__ Cb2, int ldcb2,
    const float* __restrict__ aux, int ldaux,
    int K, int mode)
{
    __shared__ u16 Asl[2][128 * LDK];
    __shared__ u16 Bsl[2][64 * LDK];
    const int tid = threadIdx.x;
    int bxs, bys;
    xcd_swz(bxs, bys);
    const int bm = bys * 128, bn = bxs * 64;
    const int lane = tid & 63, wave = tid >> 6;
    const int wy = wave >> 1, wx = wave & 1;
    const int qd = lane >> 4, ln16 = lane & 15;

    f32x4 acc[4][2];
#pragma unroll
    for (int i = 0; i < 4; i++)
#pragma unroll
        for (int j = 0; j < 2; j++)
#pragma unroll
            for (int r = 0; r < 4; r++) acc[i][j][r] = 0.f;

    const u16* Ab = A  + (size_t)bm * lda;
    const u16* Bb = Bt + (size_t)bn * ldb;
    stage128x32(Ab, lda, Asl[0], tid);
    stage64x32(Bb, ldb, Bsl[0], tid);
    __syncthreads();
    int cur = 0;
    for (int k0 = 0; k0 < K; k0 += 32) {
        if (k0 + 32 < K) {
            stage128x32(Ab + k0 + 32, lda, Asl[cur ^ 1], tid);
            stage64x32(Bb + k0 + 32, ldb, Bsl[cur ^ 1], tid);
        }
        const u16* Ac = Asl[cur];
        const u16* Bc = Bsl[cur];
        short8 af[4], bf_[2];
#pragma unroll
        for (int i = 0; i < 4; i++)
            af[i]  = *(const short8*)&Ac[(wy * 64 + i * 16 + ln16) * LDK + qd * 8];
#pragma unroll
        for (int j = 0; j < 2; j++)
            bf_[j] = *(const short8*)&Bc[(wx * 32 + j * 16 + ln16) * LDK + qd * 8];
#pragma unroll
        for (int i = 0; i < 4; i++)
#pragma unroll
            for (int j = 0; j < 2; j++)
                acc[i][j] = __builtin_amdgcn_mfma_f32_16x16x32_bf16(af[i], bf_[j], acc[i][j], 0, 0, 0);
        __syncthreads();
        cur ^= 1;
    }

#pragma unroll
    for (int i = 0; i < 4; i++) {
#pragma unroll
        for (int j = 0; j < 2; j++) {
            const int col = bn + wx * 32 + j * 16 + ln16;
            const float b_ = bias ? bias[col] : 0.f;
#pragma unroll
            for (int r = 0; r < 4; r++) {
                const int row = bm + wy * 64 + i * 16 + qd * 4 + r;
                float v = acc[i][j][r] + b_;
                if (mode == 1) v = 0.5f * v * (1.0f + erff(v * 0.7071067811865476f));
                if (Cf)  Cf[(size_t)row * ldc + col] = v;
                if (Cb)  Cb[(size_t)row * ldcb + col] = f2bu(v);
                if (Cb2) Cb2[(size_t)row * ldcb2 + col] =
                             f2bu(aux[(size_t)row * ldaux + col] - v);
            }
        }
    }
}

// ---------------------------------------------------------------------------
// Dual-B fused gate GEMM: C = sigmoid(A@B1 + b1) * (A@B2 + b2), fp32 out.
// 128x64 tile, A staged once, 16 MFMA/iter/wave, dbuf prefetch.
// ---------------------------------------------------------------------------
__global__ __launch_bounds__(256) void gemm_bf2(
    const u16* __restrict__ A, int lda,
    const u16* __restrict__ B1t, const u16* __restrict__ B2t, int ldb,
    const float* __restrict__ bias1, const float* __restrict__ bias2,
    float* __restrict__ Cf, int ldc, int K)
{
    __shared__ u16 Asl[2][128 * LDK];
    __shared__ u16 B1sl[2][64 * LDK];
    __shared__ u16 B2sl[2][64 * LDK];
    const int tid = threadIdx.x;
    int bxs, bys;
    xcd_swz(bxs, bys);
    const int bm = bys * 128, bn = bxs * 64;
    const int lane = tid & 63, wave = tid >> 6;
    const int wy = wave >> 1, wx = wave & 1;
    const int qd = lane >> 4, ln16 = lane & 15;

    f32x4 acc1[4][2], acc2[4][2];
#pragma unroll
    for (int i = 0; i < 4; i++)
#pragma unroll
        for (int j = 0; j < 2; j++)
#pragma unroll
            for (int r = 0; r < 4; r++) { acc1[i][j][r] = 0.f; acc2[i][j][r] = 0.f; }

    const u16* Ab  = A   + (size_t)bm * lda;
    const u16* B1b = B1t + (size_t)bn * ldb;
    const u16* B2b = B2t + (size_t)bn * ldb;
    stage128x32(Ab,  lda, Asl[0],  tid);
    stage64x32(B1b, ldb, B1sl[0], tid);
    stage64x32(B2b, ldb, B2sl[0], tid);
    __syncthreads();
    int cur = 0;
    for (int k0 = 0; k0 < K; k0 += 32) {
        if (k0 + 32 < K) {
            stage128x32(Ab  + k0 + 32, lda, Asl[cur ^ 1],  tid);
            stage64x32(B1b + k0 + 32, ldb, B1sl[cur ^ 1], tid);
            stage64x32(B2b + k0 + 32, ldb, B2sl[cur ^ 1], tid);
        }
        const u16* Ac  = Asl[cur];
        const u16* B1c = B1sl[cur];
        const u16* B2c = B2sl[cur];
        short8 af[4], b1f[2], b2f[2];
#pragma unroll
        for (int i = 0; i < 4; i++)
            af[i]  = *(const short8*)&Ac [(wy * 64 + i * 16 + ln16) * LDK + qd * 8];
#pragma unroll
        for (int j = 0; j < 2; j++) {
            b1f[j] = *(const short8*)&B1c[(wx * 32 + j * 16 + ln16) * LDK + qd * 8];
            b2f[j] = *(const short8*)&B2c[(wx * 32 + j * 16 + ln16) * LDK + qd * 8];
        }
#pragma unroll
        for (int i = 0; i < 4; i++)
#pragma unroll
            for (int j = 0; j < 2; j++) {
                acc1[i][j] = __builtin_amdgcn_mfma_f32_16x16x32_bf16(af[i], b1f[j], acc1[i][j], 0, 0, 0);
                acc2[i][j] = __builtin_amdgcn_mfma_f32_16x16x32_bf16(af[i], b2f[j], acc2[i][j], 0, 0, 0);
            }
        __syncthreads();
        cur ^= 1;
    }

#pragma unroll
    for (int i = 0; i < 4; i++) {
#pragma unroll
        for (int j = 0; j < 2; j++) {
            const int col = bn + wx * 32 + j * 16 + ln16;
            const float b1_ = bias1[col], b2_ = bias2[col];
#pragma unroll
            for (int r = 0; r < 4; r++) {
                const int row = bm + wy * 64 + i * 16 + qd * 4 + r;
                const float g = 1.0f / (1.0f + expf(-(acc1[i][j][r] + b1_)));
                Cf[(size_t)row * ldc + col] = g * (acc2[i][j][r] + b2_);
            }
        }
    }
}

// ---------------------------------------------------------------------------
// LayerNorm over 512 features. in1b optional bf16 add. fp32 + optional bf16 out.
// ---------------------------------------------------------------------------
__global__ __launch_bounds__(256) void ln_kernel(
    const float* __restrict__ in0, int ld0,
    const u16* __restrict__ in1b, int ld1b,
    const float* __restrict__ g, const float* __restrict__ bta,
    float* __restrict__ outf, int ldo,
    u16* __restrict__ outb, int ldob)
{
    int row = blockIdx.x, tid = threadIdx.x;
    const float* p0 = in0 + (size_t)row * ld0;
    float v0 = p0[tid], v1 = p0[tid + 256];
    if (in1b) {
        const u16* p1 = in1b + (size_t)row * ld1b;
        union { unsigned u; float f; } c0, c1;
        c0.u = ((unsigned)p1[tid]) << 16;
        c1.u = ((unsigned)p1[tid + 256]) << 16;
        v0 += c0.f; v1 += c1.f;
    }
    float s = v0 + v1, sq = v0 * v0 + v1 * v1;
#pragma unroll
    for (int o = 32; o > 0; o >>= 1) {
        s  += __shfl_xor(s, o);
        sq += __shfl_xor(sq, o);
    }
    __shared__ float red[8];
    int wid = tid >> 6;
    if ((tid & 63) == 0) { red[wid] = s; red[4 + wid] = sq; }
    __syncthreads();
    s  = red[0] + red[1] + red[2] + red[3];
    sq = red[4] + red[5] + red[6] + red[7];
    float mean = s * (1.0f / 512.0f);
    float var  = sq * (1.0f / 512.0f) - mean * mean;
    float rstd = rsqrtf(var + 1e-5f);
    float o0 = (v0 - mean) * rstd * g[tid] + bta[tid];
    float o1 = (v1 - mean) * rstd * g[tid + 256] + bta[tid + 256];
    if (outf) {
        outf[(size_t)row * ldo + tid]       = o0;
        outf[(size_t)row * ldo + tid + 256] = o1;
    }
    if (outb) {
        outb[(size_t)row * ldob + tid]       = f2bu(o0);
        outb[(size_t)row * ldob + tid + 256] = f2bu(o1);
    }
}

// ---------------------------------------------------------------------------
// MFMA flash attention, q==k==v bf16, head_dim 64. exp2-domain softmax.
// S^T orientation: mfma(K_frag, Q_frag) -> lane holds one q row's 16 scores,
// so key-reduction is in-register + 2 shfl; P packs into b64 LDS writes.
// Writes bf16 new_x into catb[:, 0:512] (ld 1024).
// ---------------------------------------------------------------------------
#define AP 80   /* LDS pitch in bf16 elems: rows 16B-aligned, 2-way-max banks */

__global__ __launch_bounds__(256) void attn_mfma(const u16* __restrict__ qall,
                                                 u16* __restrict__ catb) {
    __shared__ u16 Ks[64 * AP];        // [key][d]
    __shared__ u16 KsT[64 * AP];       // [d][key]
    __shared__ u16 Pw[4][16 * AP];     // per-wave P [q][key]

    const int bid = blockIdx.x;
    const int lt = bid & 15, hh = (bid >> 4) & 7, bb = bid >> 7;
    const int q0 = lt * 64;
    const int tid = threadIdx.x;
    const int wave = tid >> 6, lane = tid & 63;
    const int quad = lane >> 4, ln16 = lane & 15;

    const u16* qh = qall + (size_t)bb * SEQ * EDIM + hh * 64;

    const u16* qrow = qh + (size_t)(q0 + wave * 16 + ln16) * EDIM + quad * 8;
    const short8 aq0 = *(const short8*)(qrow);
    const short8 aq1 = *(const short8*)(qrow + 32);

    f32x4 oacc[4];
    float m_run = -1e30f, l_run = 0.f;   // softmax state for q = ln16 (repl. per quad)
#pragma unroll
    for (int j = 0; j < 4; j++)
#pragma unroll
        for (int r = 0; r < 4; r++) oacc[j][r] = 0.f;

    const int sr  = tid & 63;
    const int scq = (tid >> 6) * 16;

    for (int s0 = 0; s0 < SEQ; s0 += 64) {
        __syncthreads();
        {
            const u16* krow = qh + (size_t)(s0 + sr) * EDIM + scq;
            uint4 v0 = *(const uint4*)(krow);
            uint4 v1 = *(const uint4*)(krow + 8);
            *(uint4*)&Ks[sr * AP + scq]     = v0;
            *(uint4*)&Ks[sr * AP + scq + 8] = v1;
            const u16* h0 = (const u16*)&v0;
            const u16* h1 = (const u16*)&v1;
#pragma unroll
            for (int i = 0; i < 8; i++) KsT[(scq + i) * AP + sr]     = h0[i];
#pragma unroll
            for (int i = 0; i < 8; i++) KsT[(scq + 8 + i) * AP + sr] = h1[i];
        }
        __syncthreads();

        // S^T[j]: lane (quad,ln16), reg r = scores[key=s0+j*16+quad*4+r][q=ln16]
        f32x4 S[4];
#pragma unroll
        for (int j = 0; j < 4; j++) {
            const int krw = (j * 16 + ln16) * AP + quad * 8;
            short8 a0 = *(const short8*)&Ks[krw];
            short8 a1 = *(const short8*)&Ks[krw + 32];
            f32x4 c = {0.f, 0.f, 0.f, 0.f};
            c = __builtin_amdgcn_mfma_f32_16x16x32_bf16(a0, aq0, c, 0, 0, 0);
            c = __builtin_amdgcn_mfma_f32_16x16x32_bf16(a1, aq1, c, 0, 0, 0);
            S[j] = c;
        }

        // online softmax for q = ln16: reduce 16 in-reg values + 2 shfl (quads)
        float mx = S[0][0];
#pragma unroll
        for (int j = 0; j < 4; j++)
#pragma unroll
            for (int r = 0; r < 4; r++) mx = fmaxf(mx, S[j][r]);
        mx = fmaxf(mx, __shfl_xor(mx, 16));
        mx = fmaxf(mx, __shfl_xor(mx, 32));
        const float mn = fmaxf(m_run, mx);
        const float al = exp2f((m_run - mn) * ATT_SCL);
        m_run = mn;
        const float ns = -mn * ATT_SCL;
        float p[4][4];
        float rs = 0.f;
#pragma unroll
        for (int j = 0; j < 4; j++)
#pragma unroll
            for (int r = 0; r < 4; r++) {
                p[j][r] = exp2f(fmaf(S[j][r], ATT_SCL, ns));
                rs += p[j][r];
            }
        rs += __shfl_xor(rs, 16);
        rs += __shfl_xor(rs, 32);
        l_run = l_run * al + rs;

        // pack P -> Pw[wave][q=ln16][key]: 4 consecutive keys per (j)
#pragma unroll
        for (int j = 0; j < 4; j++) {
            unsigned w0 = cvtpk_bf16(p[j][0], p[j][1]);
            unsigned w1 = cvtpk_bf16(p[j][2], p[j][3]);
            *(uint2*)&Pw[wave][ln16 * AP + j * 16 + quad * 4] = make_uint2(w0, w1);
        }

        // redistribute al to the O-accumulator's q index (q = quad*4+r)
        float alq[4];
#pragma unroll
        for (int r = 0; r < 4; r++) alq[r] = __shfl(al, quad * 4 + r);
#pragma unroll
        for (int j = 0; j < 4; j++)
#pragma unroll
            for (int r = 0; r < 4; r++) oacc[j][r] *= alq[r];

        // PV: A = P[q=ln16][key=quad*8+i], B = V^T fragments from KsT
        short8 pa0 = *(const short8*)&Pw[wave][ln16 * AP + quad * 8];
        short8 pa1 = *(const short8*)&Pw[wave][ln16 * AP + 32 + quad * 8];

#pragma unroll
        for (int j = 0; j < 4; j++) {
            const int drw = (j * 16 + ln16) * AP + quad * 8;
            short8 b0 = *(const short8*)&KsT[drw];
            short8 b1 = *(const short8*)&KsT[drw + 32];
            oacc[j] = __builtin_amdgcn_mfma_f32_16x16x32_bf16(pa0, b0, oacc[j], 0, 0, 0);
            oacc[j] = __builtin_amdgcn_mfma_f32_16x16x32_bf16(pa1, b1, oacc[j], 0, 0, 0);
        }
    }

    const float linv = 1.0f / l_run;
    float invq[4];
#pragma unroll
    for (int r = 0; r < 4; r++) invq[r] = __shfl(linv, quad * 4 + r);
#pragma unroll
    for (int r = 0; r < 4; r++) {
        const int row = bb * SEQ + q0 + wave * 16 + quad * 4 + r;
#pragma unroll
        for (int j = 0; j < 4; j++) {
            const int col = hh * 64 + j * 16 + ln16;
            catb[(size_t)row * E2DIM + col] = f2bu(oacc[j][r] * invq[r]);
        }
    }
}

// ---------------------------------------------------------------------------
// Host launch
// ---------------------------------------------------------------------------
extern "C" void kernel_launch(void* const* d_in, const int* in_sizes, int n_in,
                              void* d_out, int out_size, void* d_ws, size_t ws_size,
                              hipStream_t stream)
{
    // ---- workspace layout (float units) ----
    const size_t OFF_MT0 = 0;
    const size_t OFF_MT1 = OFF_MT0 + 131072;
    const size_t OFF_MT2 = OFF_MT1 + 131072;
    const size_t OFF_MT3 = OFF_MT2 + 131072;
    const size_t OFF_MT4 = OFF_MT3 + 131072;
    const size_t OFF_MT5 = OFF_MT4 + 524288;
    const size_t OFF_XB  = OFF_MT5 + 524288;        // x_bf / x1_bf (bf16 8192x512)
    const size_t OFF_CB  = OFF_XB + 2097152;        // cat bf16 [8192,1024]
    const size_t OFF_BQ  = OFF_CB + 4194304;        // q bf16 -> x2 bf16
    const size_t OFF_BN  = OFF_BQ + 4194304;        // fold t1 scratch -> h fp32
    const size_t OFF_BC  = OFF_BN + 4194304;        // fold t2 scratch -> x1 fp32
    const size_t OFF_P   = OFF_BC + 4194304;        // fp32-converted inputs

    float* W = (float*)d_ws;
    u16* MT[6] = {(u16*)(W + OFF_MT0), (u16*)(W + OFF_MT1), (u16*)(W + OFF_MT2),
                  (u16*)(W + OFF_MT3), (u16*)(W + OFF_MT4), (u16*)(W + OFF_MT5)};
    u16*   XB  = (u16*)(W + OFF_XB);
    u16*   CB  = (u16*)(W + OFF_CB);
    u16*   QB  = (u16*)(W + OFF_BQ);   // q bf16; later x2 bf16 (sequential reuse)
    float* BN  = W + OFF_BN;           // h fp32 (after fold)
    float* BC  = W + OFF_BC;           // x1 fp32 (after fold)

    float* F[23];
    CvtBatch cb;
    int pre = 0;
    for (int i = 0; i < 23 && i < n_in; i++) {
        cb.pre4[i] = pre;
        F[i] = W + OFF_P + (size_t)pre * 4;
        cb.src[i] = d_in[i];
        cb.dst[i] = (float4*)F[i];
        pre += in_sizes[i] / 4;
    }
    cb.pre4[23] = pre;
    const int total4 = pre;
    int* FLAG = (int*)(W + OFF_P + (size_t)total4 * 4);

    if (n_in < 23) return;
    if (ws_size < (OFF_P + (size_t)total4 * 4 + 16) * sizeof(float)) return;

    detect_dtype<<<1, 256, 0, stream>>>((const u16*)d_in[0], FLAG);
    cvt_all<<<(total4 + 255) / 256, 256, 0, stream>>>(cb, total4, FLAG);
    f2b_kernel<<<(ROWS * EDIM / 4 + 255) / 256, 256, 0, stream>>>(F[0], XB, ROWS * EDIM / 4);

    // ---- fold (3 batched launches): scratch overlays BN/BC (dead here) ----
    FoldBatch fb;
    {
        const int wi[6] = {1, 4, 7, 10, 13, 16};
        u16* T1 = (u16*)BN;
        u16* T2 = (u16*)BC;
        size_t off = 0;
        for (int s = 0; s < 6; s++) {
            const int n = (s < 4) ? 512 : 1024;
            fb.w[s]  = F[wi[s]];
            fb.fw[s] = F[wi[s] + 1];
            fb.t1[s] = T1 + off;
            fb.t2[s] = T2 + off;
            fb.mt[s] = MT[s];
            fb.n[s]  = n;
            fb.lg[s] = (s < 4) ? 9 : 10;
            fb.sc[s] = (s < 4) ? 0.04419417382415922f : 0.03125f;
            off += (size_t)n * n;
        }
    }
    fold_trconv<<<dim3(32, 32, 6), 256, 0, stream>>>(fb);
    fold_circ<<<dim3(4096, 1, 6), 256, 0, stream>>>(fb);
    fold_gemm<<<dim3(8, 8, 6), 256, 0, stream>>>(fb);

    float* out0 = (float*)d_out;                       // LN(h): [8192,512]
    float* out1 = (float*)d_out + (size_t)ROWS * EDIM; // out:   [8192,1024]

    // q = x @ M0 + attn_fb                                  -> QB (bf16)
    gemm_bf<<<dim3(8, 64), 256, 0, stream>>>(
        XB, 512, MT[0], 512, F[3], nullptr, 0, QB, 512, nullptr, 0, nullptr, 0, 512, 0);
    // attention -> cat bf16 [:, :512]
    attn_mfma<<<1024, 256, 0, stream>>>(QB, CB);
    // x1 = LN(x + newx; n1)                                 -> BC fp32 + XB bf16
    ln_kernel<<<8192, 256, 0, stream>>>(F[0], 512, CB, 1024, F[19], F[20],
                                        BC, 512, XB, 512);
    // x_ln = gelu(x1 @ M1 + b); cat[:,512:]=bf16(v); x2=bf16(x1-v) -> QB
    gemm_bf<<<dim3(8, 64), 256, 0, stream>>>(
        XB, 512, MT[1], 512, F[6], nullptr, 0, CB + 512, 1024, QB, 512, BC, 512, 512, 1);
    // h = sigmoid(x2@M2+b2) * (x2@M3+b3)                     -> BN fp32
    gemm_bf2<<<dim3(8, 64), 256, 0, stream>>>(
        QB, 512, MT[2], MT[3], 512, F[9], F[12], BN, 512, 512);
    // out0 = LN(h; n2)                                       -> d_out
    ln_kernel<<<8192, 256, 0, stream>>>(BN, 512, nullptr, 0, F[21], F[22],
                                        out0, 512, nullptr, 0);
    // out1 = sigmoid(cat@M4+b4) * (cat@M5+b5)                -> d_out+4M
    gemm_bf2<<<dim3(16, 64), 256, 0, stream>>>(
        CB, 1024, MT[4], MT[5], 1024, F[15], F[18], out1, 1024, 1024);
}

// Round 5
// 334.412 us; speedup vs baseline: 1.3688x; 1.0417x over previous
//
#include <hip/hip_runtime.h>
#include <hip/hip_bf16.h>
#include <math.h>

typedef __hip_bfloat16 bf16;
typedef unsigned short u16;
typedef __attribute__((ext_vector_type(8))) short short8;
typedef __attribute__((ext_vector_type(4))) float f32x4;

#define NB      8
#define SEQ     1024
#define EDIM    512
#define E2DIM   1024
#define ROWS    8192
#define INV_SQRT_E 0.04419417382415922f
#define ATT_SCL    0.06375985678148161f   /* INV_SQRT_E * log2(e) */

__device__ inline u16 f2bu(float f) {           // fp32 -> bf16 bits, RNE
    union { float f; unsigned u; } c; c.f = f;
    return (u16)((c.u + 0x7FFF + ((c.u >> 16) & 1)) >> 16);
}

__device__ __forceinline__ unsigned cvtpk_bf16(float lo, float hi) {
    unsigned r;
    asm("v_cvt_pk_bf16_f32 %0, %1, %2" : "=v"(r) : "v"(lo), "v"(hi));
    return r;
}

// counted-vmcnt pipeline fences (T4): loads stay in flight across barriers.
#define VMCNT(N) do { \
    asm volatile("s_waitcnt vmcnt(" #N ")" ::: "memory"); \
    __builtin_amdgcn_sched_barrier(0); \
    __builtin_amdgcn_s_barrier(); \
    __builtin_amdgcn_sched_barrier(0); } while (0)

#define LGKM0_BAR() do { \
    asm volatile("s_waitcnt lgkmcnt(0)" ::: "memory"); \
    __builtin_amdgcn_sched_barrier(0); \
    __builtin_amdgcn_s_barrier(); \
    __builtin_amdgcn_sched_barrier(0); } while (0)

// ---------------------------------------------------------------------------
// Input dtype autodetect (proved inputs are fp32; kept as cheap insurance).
// ---------------------------------------------------------------------------
__global__ __launch_bounds__(256) void detect_dtype(const u16* __restrict__ x,
                                                    int* __restrict__ flag) {
    int t = threadIdx.x;
    int cnt = 0;
    for (int k = t; k < 8192; k += 256) {
        int e = (x[k] >> 7) & 0xFF;
        if (e >= 0xC0) cnt++;
    }
#pragma unroll
    for (int o = 32; o > 0; o >>= 1) cnt += __shfl_xor(cnt, o);
    __shared__ int red[4];
    if ((t & 63) == 0) red[t >> 6] = cnt;
    __syncthreads();
    if (t == 0) flag[0] = (red[0] + red[1] + red[2] + red[3] > 100) ? 1 : 0;
}

// ---------------------------------------------------------------------------
// Batch conversion of all 23 inputs -> fp32 workspace (dtype-adaptive).
// ---------------------------------------------------------------------------
struct CvtBatch {
    const void* src[23];
    float4*     dst[23];
    int         pre4[24];
};

__global__ __launch_bounds__(256) void cvt_all(CvtBatch a, int total4,
                                               const int* __restrict__ flag) {
    int t = blockIdx.x * 256 + threadIdx.x;
    if (t >= total4) return;
    int lo = 0;
    while (t >= a.pre4[lo + 1]) lo++;
    int li = t - a.pre4[lo];
    if (flag[0]) {
        a.dst[lo][li] = ((const float4*)a.src[lo])[li];
    } else {
        ushort4 u = ((const ushort4*)a.src[lo])[li];
        union { unsigned int i; float f; } c;
        float4 o;
        c.i = ((unsigned)u.x) << 16; o.x = c.f;
        c.i = ((unsigned)u.y) << 16; o.y = c.f;
        c.i = ((unsigned)u.z) << 16; o.z = c.f;
        c.i = ((unsigned)u.w) << 16; o.w = c.f;
        a.dst[lo][li] = o;
    }
}

// fp32 -> bf16 elementwise, n/4 threads
__global__ __launch_bounds__(256) void f2b_kernel(const float* __restrict__ src,
                                                  u16* __restrict__ dst, int n4) {
    int i = blockIdx.x * 256 + threadIdx.x;
    if (i >= n4) return;
    float4 a = ((const float4*)src)[i];
    ushort4 o;
    o.x = f2bu(a.x); o.y = f2bu(a.y); o.z = f2bu(a.z); o.w = f2bu(a.w);
    ((ushort4*)dst)[i] = o;
}

// ---------------------------------------------------------------------------
// async global->LDS staging (linear LDS, width=16).
// LDS dest is wave-uniform base + lane*16 (HW rule); global src is per-lane.
// ---------------------------------------------------------------------------
#define LDK 32   /* linear LDS row: 32 bf16 = 64 B */

__device__ __forceinline__ void stage128x32(const u16* g, int ld, u16* lds, int tid) {
    const int w = tid >> 6;              // wave id (uniform within wave)
    const int l = tid & 63;
    const int r = w * 16 + (l >> 2);     // row covered by this lane
    const int c = (l & 3) * 8;           // 16B chunk within row
    const u16* g0 = g + (size_t)r * ld + c;
    u16* l0 = lds + w * 16 * LDK;        // wave-uniform LDS base
    __builtin_amdgcn_global_load_lds(
        (const __attribute__((address_space(1))) void*)g0,
        (__attribute__((address_space(3))) void*)l0, 16, 0, 0);
    const u16* g1 = g0 + (size_t)64 * ld;
    u16* l1 = l0 + 64 * LDK;
    __builtin_amdgcn_global_load_lds(
        (const __attribute__((address_space(1))) void*)g1,
        (__attribute__((address_space(3))) void*)l1, 16, 0, 0);
}

__device__ __forceinline__ void stage64x32(const u16* g, int ld, u16* lds, int tid) {
    const int w = tid >> 6;
    const int l = tid & 63;
    const int r = w * 16 + (l >> 2);
    const int c = (l & 3) * 8;
    const u16* g0 = g + (size_t)r * ld + c;
    u16* l0 = lds + w * 16 * LDK;
    __builtin_amdgcn_global_load_lds(
        (const __attribute__((address_space(1))) void*)g0,
        (__attribute__((address_space(3))) void*)l0, 16, 0, 0);
}

// Bijective XCD-aware block swizzle (requires gridDim.x*gridDim.y % 8 == 0).
// Consecutive by-rows land on the same XCD L2 so the shared A-panel is
// fetched once per XCD, not 8x.
__device__ __forceinline__ void xcd_swz(int& bx, int& by) {
    const int nx  = gridDim.x;
    const int nwg = nx * gridDim.y;
    const int lid = blockIdx.y * nx + blockIdx.x;
    const int q   = nwg >> 3;
    const int s   = (lid & 7) * q + (lid >> 3);
    bx = s % nx;
    by = s / nx;
}

// ---------------------------------------------------------------------------
// Fold batch: 6 spectral layers, z-indexed kernels (3 launches total).
// Mt[s][o][j] = sc * sum_m fw[m][o] * w[(m-j) mod n]
// ---------------------------------------------------------------------------
struct FoldBatch {
    const float* w[6];
    const float* fw[6];
    u16* t1[6];    // fwT bf16: t1[o][m] = bf16(fw[m][o])
    u16* t2[6];    // circ bf16: t2[j][m] = bf16(w[(m-j) mod n])
    u16* mt[6];    // output Mt bf16 [n][n]
    int  n[6], lg[6];
    float sc[6];
};

__global__ __launch_bounds__(256) void fold_trconv(FoldBatch fb) {
    const int z = blockIdx.z;
    const int n = fb.n[z];
    const int bx = blockIdx.x * 32, by = blockIdx.y * 32;
    if (bx >= n || by >= n) return;
    __shared__ float t[32][33];
    const int tx = threadIdx.x & 31, ty = threadIdx.x >> 5;   // 32x8
    const float* src = fb.fw[z];
    u16* dst = fb.t1[z];
#pragma unroll
    for (int r = 0; r < 32; r += 8)
        t[ty + r][tx] = src[(size_t)(by + ty + r) * n + bx + tx];
    __syncthreads();
#pragma unroll
    for (int r = 0; r < 32; r += 8)
        dst[(size_t)(bx + ty + r) * n + by + tx] = f2bu(t[tx][ty + r]);
}

__global__ __launch_bounds__(256) void fold_circ(FoldBatch fb) {
    const int z = blockIdx.z;
    const int n = fb.n[z], lg = fb.lg[z];
    int idx = blockIdx.x * 256 + threadIdx.x;
    if (idx >= n * n) return;
    int mask = n - 1;
    int m = idx & mask;
    int j = idx >> lg;
    fb.t2[z][idx] = f2bu(fb.w[z][(m - j) & mask]);
}

__global__ __launch_bounds__(256) void fold_gemm(FoldBatch fb) {
    const int z = blockIdx.z;
    const int n = fb.n[z];
    const int bm = blockIdx.y * 128, bn = blockIdx.x * 128;
    if (bm >= n || bn >= n) return;
    const u16* A  = fb.t1[z];
    const u16* Bt = fb.t2[z];
    u16* Mt = fb.mt[z];
    const float scale = fb.sc[z];

    __shared__ u16 Asl[2][128 * LDK];
    __shared__ u16 Bsl[2][128 * LDK];
    const int tid = threadIdx.x;
    const int lane = tid & 63, wave = tid >> 6;
    const int wy = wave >> 1, wx = wave & 1;
    const int qd = lane >> 4, ln16 = lane & 15;

    f32x4 acc[4][4];
#pragma unroll
    for (int i = 0; i < 4; i++)
#pragma unroll
        for (int j = 0; j < 4; j++)
#pragma unroll
            for (int r = 0; r < 4; r++) acc[i][j][r] = 0.f;

    const u16* Ab = A  + (size_t)bm * n;
    const u16* Bb = Bt + (size_t)bn * n;
    const int nt = n >> 5;
    stage128x32(Ab, n, Asl[0], tid);
    stage128x32(Bb, n, Bsl[0], tid);
    stage128x32(Ab + 32, n, Asl[1], tid);
    stage128x32(Bb + 32, n, Bsl[1], tid);
    int cur = 0;
    for (int t = 0; t < nt - 1; ++t) {
        VMCNT(4);                           // tile t landed; t+1 in flight
        const u16* Ac = Asl[cur];
        const u16* Bc = Bsl[cur];
        short8 af[4], bf_[4];
#pragma unroll
        for (int i = 0; i < 4; i++) {
            af[i]  = *(const short8*)&Ac[(wy * 64 + i * 16 + ln16) * LDK + qd * 8];
            bf_[i] = *(const short8*)&Bc[(wx * 64 + i * 16 + ln16) * LDK + qd * 8];
        }
        LGKM0_BAR();                        // all waves done reading buf[cur]
        if (t + 2 < nt) {
            const int k2 = (t + 2) * 32;
            stage128x32(Ab + k2, n, Asl[cur], tid);
            stage128x32(Bb + k2, n, Bsl[cur], tid);
        }
#pragma unroll
        for (int i = 0; i < 4; i++)
#pragma unroll
            for (int j = 0; j < 4; j++)
                acc[i][j] = __builtin_amdgcn_mfma_f32_16x16x32_bf16(af[i], bf_[j], acc[i][j], 0, 0, 0);
        cur ^= 1;
    }
    VMCNT(0);                               // last tile fully landed
    {
        const u16* Ac = Asl[cur];
        const u16* Bc = Bsl[cur];
        short8 af[4], bf_[4];
#pragma unroll
        for (int i = 0; i < 4; i++) {
            af[i]  = *(const short8*)&Ac[(wy * 64 + i * 16 + ln16) * LDK + qd * 8];
            bf_[i] = *(const short8*)&Bc[(wx * 64 + i * 16 + ln16) * LDK + qd * 8];
        }
#pragma unroll
        for (int i = 0; i < 4; i++)
#pragma unroll
            for (int j = 0; j < 4; j++)
                acc[i][j] = __builtin_amdgcn_mfma_f32_16x16x32_bf16(af[i], bf_[j], acc[i][j], 0, 0, 0);
    }
#pragma unroll
    for (int i = 0; i < 4; i++)
#pragma unroll
        for (int j = 0; j < 4; j++) {
            const int col = bn + wx * 64 + j * 16 + ln16;
#pragma unroll
            for (int r = 0; r < 4; r++) {
                const int row = bm + wy * 64 + i * 16 + qd * 4 + r;
                Mt[(size_t)row * n + col] = f2bu(acc[i][j][r] * scale);
            }
        }
}

// ---------------------------------------------------------------------------
// bf16 MFMA GEMM (single B): C = act( A @ B + bias ). B pre-transposed.
// 128x64 tile, BK=32, 4 waves (2x2), 2-deep counted-vmcnt pipeline.
// mode: 0 none, 1 gelu(exact).
// Optional outputs: Cf fp32, Cb bf16(v), Cb2 bf16(aux - v).
// ---------------------------------------------------------------------------
__global__ __launch_bounds__(256) void gemm_bf(
    const u16* __restrict__ A, int lda,
    const u16* __restrict__ Bt, int ldb,
    const float* __restrict__ bias,
    float* __restrict__ Cf, int ldc,
    u16* __restrict__ Cb, int ldcb,
    u16* __restrict__ Cb2, int ldcb2,
    const float* __restrict__ aux, int ldaux,
    int K, int mode)
{
    __shared__ u16 Asl[2][128 * LDK];
    __shared__ u16 Bsl[2][64 * LDK];
    const int tid = threadIdx.x;
    int bxs, bys;
    xcd_swz(bxs, bys);
    const int bm = bys * 128, bn = bxs * 64;
    const int lane = tid & 63, wave = tid >> 6;
    const int wy = wave >> 1, wx = wave & 1;
    const int qd = lane >> 4, ln16 = lane & 15;

    f32x4 acc[4][2];
#pragma unroll
    for (int i = 0; i < 4; i++)
#pragma unroll
        for (int j = 0; j < 2; j++)
#pragma unroll
            for (int r = 0; r < 4; r++) acc[i][j][r] = 0.f;

    const u16* Ab = A  + (size_t)bm * lda;
    const u16* Bb = Bt + (size_t)bn * ldb;
    const int nt = K >> 5;
    stage128x32(Ab, lda, Asl[0], tid);
    stage64x32(Bb, ldb, Bsl[0], tid);
    stage128x32(Ab + 32, lda, Asl[1], tid);
    stage64x32(Bb + 32, ldb, Bsl[1], tid);
    int cur = 0;
    for (int t = 0; t < nt - 1; ++t) {
        VMCNT(3);
        const u16* Ac = Asl[cur];
        const u16* Bc = Bsl[cur];
        short8 af[4], bf_[2];
#pragma unroll
        for (int i = 0; i < 4; i++)
            af[i]  = *(const short8*)&Ac[(wy * 64 + i * 16 + ln16) * LDK + qd * 8];
#pragma unroll
        for (int j = 0; j < 2; j++)
            bf_[j] = *(const short8*)&Bc[(wx * 32 + j * 16 + ln16) * LDK + qd * 8];
        LGKM0_BAR();
        if (t + 2 < nt) {
            const int k2 = (t + 2) * 32;
            stage128x32(Ab + k2, lda, Asl[cur], tid);
            stage64x32(Bb + k2, ldb, Bsl[cur], tid);
        }
#pragma unroll
        for (int i = 0; i < 4; i++)
#pragma unroll
            for (int j = 0; j < 2; j++)
                acc[i][j] = __builtin_amdgcn_mfma_f32_16x16x32_bf16(af[i], bf_[j], acc[i][j], 0, 0, 0);
        cur ^= 1;
    }
    VMCNT(0);
    {
        const u16* Ac = Asl[cur];
        const u16* Bc = Bsl[cur];
        short8 af[4], bf_[2];
#pragma unroll
        for (int i = 0; i < 4; i++)
            af[i]  = *(const short8*)&Ac[(wy * 64 + i * 16 + ln16) * LDK + qd * 8];
#pragma unroll
        for (int j = 0; j < 2; j++)
            bf_[j] = *(const short8*)&Bc[(wx * 32 + j * 16 + ln16) * LDK + qd * 8];
#pragma unroll
        for (int i = 0; i < 4; i++)
#pragma unroll
            for (int j = 0; j < 2; j++)
                acc[i][j] = __builtin_amdgcn_mfma_f32_16x16x32_bf16(af[i], bf_[j], acc[i][j], 0, 0, 0);
    }

#pragma unroll
    for (int i = 0; i < 4; i++) {
#pragma unroll
        for (int j = 0; j < 2; j++) {
            const int col = bn + wx * 32 + j * 16 + ln16;
            const float b_ = bias ? bias[col] : 0.f;
#pragma unroll
            for (int r = 0; r < 4; r++) {
                const int row = bm + wy * 64 + i * 16 + qd * 4 + r;
                float v = acc[i][j][r] + b_;
                if (mode == 1) v = 0.5f * v * (1.0f + erff(v * 0.7071067811865476f));
                if (Cf)  Cf[(size_t)row * ldc + col] = v;
                if (Cb)  Cb[(size_t)row * ldcb + col] = f2bu(v);
                if (Cb2) Cb2[(size_t)row * ldcb2 + col] =
                             f2bu(aux[(size_t)row * ldaux + col] - v);
            }
        }
    }
}

// ---------------------------------------------------------------------------
// Dual-B fused gate GEMM: C = sigmoid(A@B1 + b1) * (A@B2 + b2), fp32 out.
// 128x64 tile, A staged once, 16 MFMA/iter/wave, 2-deep counted-vmcnt pipeline.
// ---------------------------------------------------------------------------
__global__ __launch_bounds__(256) void gemm_bf2(
    const u16* __restrict__ A, int lda,
    const u16* __restrict__ B1t, const u16* __restrict__ B2t, int ldb,
    const float* __restrict__ bias1, const float* __restrict__ bias2,
    float* __restrict__ Cf, int ldc, int K)
{
    __shared__ u16 Asl[2][128 * LDK];
    __shared__ u16 B1sl[2][64 * LDK];
    __shared__ u16 B2sl[2][64 * LDK];
    const int tid = threadIdx.x;
    int bxs, bys;
    xcd_swz(bxs, bys);
    const int bm = bys * 128, bn = bxs * 64;
    const int lane = tid & 63, wave = tid >> 6;
    const int wy = wave >> 1, wx = wave & 1;
    const int qd = lane >> 4, ln16 = lane & 15;

    f32x4 acc1[4][2], acc2[4][2];
#pragma unroll
    for (int i = 0; i < 4; i++)
#pragma unroll
        for (int j = 0; j < 2; j++)
#pragma unroll
            for (int r = 0; r < 4; r++) { acc1[i][j][r] = 0.f; acc2[i][j][r] = 0.f; }

    const u16* Ab  = A   + (size_t)bm * lda;
    const u16* B1b = B1t + (size_t)bn * ldb;
    const u16* B2b = B2t + (size_t)bn * ldb;
    const int nt = K >> 5;
    stage128x32(Ab,  lda, Asl[0],  tid);
    stage64x32(B1b, ldb, B1sl[0], tid);
    stage64x32(B2b, ldb, B2sl[0], tid);
    stage128x32(Ab + 32,  lda, Asl[1],  tid);
    stage64x32(B1b + 32, ldb, B1sl[1], tid);
    stage64x32(B2b + 32, ldb, B2sl[1], tid);
    int cur = 0;
    for (int t = 0; t < nt - 1; ++t) {
        VMCNT(4);
        const u16* Ac  = Asl[cur];
        const u16* B1c = B1sl[cur];
        const u16* B2c = B2sl[cur];
        short8 af[4], b1f[2], b2f[2];
#pragma unroll
        for (int i = 0; i < 4; i++)
            af[i]  = *(const short8*)&Ac [(wy * 64 + i * 16 + ln16) * LDK + qd * 8];
#pragma unroll
        for (int j = 0; j < 2; j++) {
            b1f[j] = *(const short8*)&B1c[(wx * 32 + j * 16 + ln16) * LDK + qd * 8];
            b2f[j] = *(const short8*)&B2c[(wx * 32 + j * 16 + ln16) * LDK + qd * 8];
        }
        LGKM0_BAR();
        if (t + 2 < nt) {
            const int k2 = (t + 2) * 32;
            stage128x32(Ab  + k2, lda, Asl[cur],  tid);
            stage64x32(B1b + k2, ldb, B1sl[cur], tid);
            stage64x32(B2b + k2, ldb, B2sl[cur], tid);
        }
#pragma unroll
        for (int i = 0; i < 4; i++)
#pragma unroll
            for (int j = 0; j < 2; j++) {
                acc1[i][j] = __builtin_amdgcn_mfma_f32_16x16x32_bf16(af[i], b1f[j], acc1[i][j], 0, 0, 0);
                acc2[i][j] = __builtin_amdgcn_mfma_f32_16x16x32_bf16(af[i], b2f[j], acc2[i][j], 0, 0, 0);
            }
        cur ^= 1;
    }
    VMCNT(0);
    {
        const u16* Ac  = Asl[cur];
        const u16* B1c = B1sl[cur];
        const u16* B2c = B2sl[cur];
        short8 af[4], b1f[2], b2f[2];
#pragma unroll
        for (int i = 0; i < 4; i++)
            af[i]  = *(const short8*)&Ac [(wy * 64 + i * 16 + ln16) * LDK + qd * 8];
#pragma unroll
        for (int j = 0; j < 2; j++) {
            b1f[j] = *(const short8*)&B1c[(wx * 32 + j * 16 + ln16) * LDK + qd * 8];
            b2f[j] = *(const short8*)&B2c[(wx * 32 + j * 16 + ln16) * LDK + qd * 8];
        }
#pragma unroll
        for (int i = 0; i < 4; i++)
#pragma unroll
            for (int j = 0; j < 2; j++) {
                acc1[i][j] = __builtin_amdgcn_mfma_f32_16x16x32_bf16(af[i], b1f[j], acc1[i][j], 0, 0, 0);
                acc2[i][j] = __builtin_amdgcn_mfma_f32_16x16x32_bf16(af[i], b2f[j], acc2[i][j], 0, 0, 0);
            }
    }

#pragma unroll
    for (int i = 0; i < 4; i++) {
#pragma unroll
        for (int j = 0; j < 2; j++) {
            const int col = bn + wx * 32 + j * 16 + ln16;
            const float b1_ = bias1[col], b2_ = bias2[col];
#pragma unroll
            for (int r = 0; r < 4; r++) {
                const int row = bm + wy * 64 + i * 16 + qd * 4 + r;
                const float g = 1.0f / (1.0f + expf(-(acc1[i][j][r] + b1_)));
                Cf[(size_t)row * ldc + col] = g * (acc2[i][j][r] + b2_);
            }
        }
    }
}

// ---------------------------------------------------------------------------
// LayerNorm over 512 features. in1b optional bf16 add. fp32 + optional bf16 out.
// ---------------------------------------------------------------------------
__global__ __launch_bounds__(256) void ln_kernel(
    const float* __restrict__ in0, int ld0,
    const u16* __restrict__ in1b, int ld1b,
    const float* __restrict__ g, const float* __restrict__ bta,
    float* __restrict__ outf, int ldo,
    u16* __restrict__ outb, int ldob)
{
    int row = blockIdx.x, tid = threadIdx.x;
    const float* p0 = in0 + (size_t)row * ld0;
    float v0 = p0[tid], v1 = p0[tid + 256];
    if (in1b) {
        const u16* p1 = in1b + (size_t)row * ld1b;
        union { unsigned u; float f; } c0, c1;
        c0.u = ((unsigned)p1[tid]) << 16;
        c1.u = ((unsigned)p1[tid + 256]) << 16;
        v0 += c0.f; v1 += c1.f;
    }
    float s = v0 + v1, sq = v0 * v0 + v1 * v1;
#pragma unroll
    for (int o = 32; o > 0; o >>= 1) {
        s  += __shfl_xor(s, o);
        sq += __shfl_xor(sq, o);
    }
    __shared__ float red[8];
    int wid = tid >> 6;
    if ((tid & 63) == 0) { red[wid] = s; red[4 + wid] = sq; }
    __syncthreads();
    s  = red[0] + red[1] + red[2] + red[3];
    sq = red[4] + red[5] + red[6] + red[7];
    float mean = s * (1.0f / 512.0f);
    float var  = sq * (1.0f / 512.0f) - mean * mean;
    float rstd = rsqrtf(var + 1e-5f);
    float o0 = (v0 - mean) * rstd * g[tid] + bta[tid];
    float o1 = (v1 - mean) * rstd * g[tid + 256] + bta[tid + 256];
    if (outf) {
        outf[(size_t)row * ldo + tid]       = o0;
        outf[(size_t)row * ldo + tid + 256] = o1;
    }
    if (outb) {
        outb[(size_t)row * ldob + tid]       = f2bu(o0);
        outb[(size_t)row * ldob + tid + 256] = f2bu(o1);
    }
}

// ---------------------------------------------------------------------------
// MFMA flash attention, q==k==v bf16, head_dim 64. exp2-domain softmax.
// S^T orientation: mfma(K_frag, Q_frag) -> lane holds one q row's 16 scores,
// so key-reduction is in-register + 2 shfl; P packs into b64 LDS writes.
// Writes bf16 new_x into catb[:, 0:512] (ld 1024).
// ---------------------------------------------------------------------------
#define AP 80   /* LDS pitch in bf16 elems: rows 16B-aligned, 2-way-max banks */

__global__ __launch_bounds__(256) void attn_mfma(const u16* __restrict__ qall,
                                                 u16* __restrict__ catb) {
    __shared__ u16 Ks[64 * AP];        // [key][d]
    __shared__ u16 KsT[64 * AP];       // [d][key]
    __shared__ u16 Pw[4][16 * AP];     // per-wave P [q][key]

    const int bid = blockIdx.x;
    const int lt = bid & 15, hh = (bid >> 4) & 7, bb = bid >> 7;
    const int q0 = lt * 64;
    const int tid = threadIdx.x;
    const int wave = tid >> 6, lane = tid & 63;
    const int quad = lane >> 4, ln16 = lane & 15;

    const u16* qh = qall + (size_t)bb * SEQ * EDIM + hh * 64;

    const u16* qrow = qh + (size_t)(q0 + wave * 16 + ln16) * EDIM + quad * 8;
    const short8 aq0 = *(const short8*)(qrow);
    const short8 aq1 = *(const short8*)(qrow + 32);

    f32x4 oacc[4];
    float m_run = -1e30f, l_run = 0.f;   // softmax state for q = ln16 (repl. per quad)
#pragma unroll
    for (int j = 0; j < 4; j++)
#pragma unroll
        for (int r = 0; r < 4; r++) oacc[j][r] = 0.f;

    const int sr  = tid & 63;
    const int scq = (tid >> 6) * 16;

    for (int s0 = 0; s0 < SEQ; s0 += 64) {
        __syncthreads();
        {
            const u16* krow = qh + (size_t)(s0 + sr) * EDIM + scq;
            uint4 v0 = *(const uint4*)(krow);
            uint4 v1 = *(const uint4*)(krow + 8);
            *(uint4*)&Ks[sr * AP + scq]     = v0;
            *(uint4*)&Ks[sr * AP + scq + 8] = v1;
            const u16* h0 = (const u16*)&v0;
            const u16* h1 = (const u16*)&v1;
#pragma unroll
            for (int i = 0; i < 8; i++) KsT[(scq + i) * AP + sr]     = h0[i];
#pragma unroll
            for (int i = 0; i < 8; i++) KsT[(scq + 8 + i) * AP + sr] = h1[i];
        }
        __syncthreads();

        // S^T[j]: lane (quad,ln16), reg r = scores[key=s0+j*16+quad*4+r][q=ln16]
        f32x4 S[4];
#pragma unroll
        for (int j = 0; j < 4; j++) {
            const int krw = (j * 16 + ln16) * AP + quad * 8;
            short8 a0 = *(const short8*)&Ks[krw];
            short8 a1 = *(const short8*)&Ks[krw + 32];
            f32x4 c = {0.f, 0.f, 0.f, 0.f};
            c = __builtin_amdgcn_mfma_f32_16x16x32_bf16(a0, aq0, c, 0, 0, 0);
            c = __builtin_amdgcn_mfma_f32_16x16x32_bf16(a1, aq1, c, 0, 0, 0);
            S[j] = c;
        }

        // online softmax for q = ln16: reduce 16 in-reg values + 2 shfl (quads)
        float mx = S[0][0];
#pragma unroll
        for (int j = 0; j < 4; j++)
#pragma unroll
            for (int r = 0; r < 4; r++) mx = fmaxf(mx, S[j][r]);
        mx = fmaxf(mx, __shfl_xor(mx, 16));
        mx = fmaxf(mx, __shfl_xor(mx, 32));
        const float mn = fmaxf(m_run, mx);
        const float al = exp2f((m_run - mn) * ATT_SCL);
        m_run = mn;
        const float ns = -mn * ATT_SCL;
        float p[4][4];
        float rs = 0.f;
#pragma unroll
        for (int j = 0; j < 4; j++)
#pragma unroll
            for (int r = 0; r < 4; r++) {
                p[j][r] = exp2f(fmaf(S[j][r], ATT_SCL, ns));
                rs += p[j][r];
            }
        rs += __shfl_xor(rs, 16);
        rs += __shfl_xor(rs, 32);
        l_run = l_run * al + rs;

        // pack P -> Pw[wave][q=ln16][key]: 4 consecutive keys per (j)
#pragma unroll
        for (int j = 0; j < 4; j++) {
            unsigned w0 = cvtpk_bf16(p[j][0], p[j][1]);
            unsigned w1 = cvtpk_bf16(p[j][2], p[j][3]);
            *(uint2*)&Pw[wave][ln16 * AP + j * 16 + quad * 4] = make_uint2(w0, w1);
        }

        // redistribute al to the O-accumulator's q index (q = quad*4+r)
        float alq[4];
#pragma unroll
        for (int r = 0; r < 4; r++) alq[r] = __shfl(al, quad * 4 + r);
#pragma unroll
        for (int j = 0; j < 4; j++)
#pragma unroll
            for (int r = 0; r < 4; r++) oacc[j][r] *= alq[r];

        // PV: A = P[q=ln16][key=quad*8+i], B = V^T fragments from KsT
        short8 pa0 = *(const short8*)&Pw[wave][ln16 * AP + quad * 8];
        short8 pa1 = *(const short8*)&Pw[wave][ln16 * AP + 32 + quad * 8];

#pragma unroll
        for (int j = 0; j < 4; j++) {
            const int drw = (j * 16 + ln16) * AP + quad * 8;
            short8 b0 = *(const short8*)&KsT[drw];
            short8 b1 = *(const short8*)&KsT[drw + 32];
            oacc[j] = __builtin_amdgcn_mfma_f32_16x16x32_bf16(pa0, b0, oacc[j], 0, 0, 0);
            oacc[j] = __builtin_amdgcn_mfma_f32_16x16x32_bf16(pa1, b1, oacc[j], 0, 0, 0);
        }
    }

    const float linv = 1.0f / l_run;
    float invq[4];
#pragma unroll
    for (int r = 0; r < 4; r++) invq[r] = __shfl(linv, quad * 4 + r);
#pragma unroll
    for (int r = 0; r < 4; r++) {
        const int row = bb * SEQ + q0 + wave * 16 + quad * 4 + r;
#pragma unroll
        for (int j = 0; j < 4; j++) {
            const int col = hh * 64 + j * 16 + ln16;
            catb[(size_t)row * E2DIM + col] = f2bu(oacc[j][r] * invq[r]);
        }
    }
}

// ---------------------------------------------------------------------------
// Host launch
// ---------------------------------------------------------------------------
extern "C" void kernel_launch(void* const* d_in, const int* in_sizes, int n_in,
                              void* d_out, int out_size, void* d_ws, size_t ws_size,
                              hipStream_t stream)
{
    // ---- workspace layout (float units) ----
    const size_t OFF_MT0 = 0;
    const size_t OFF_MT1 = OFF_MT0 + 131072;
    const size_t OFF_MT2 = OFF_MT1 + 131072;
    const size_t OFF_MT3 = OFF_MT2 + 131072;
    const size_t OFF_MT4 = OFF_MT3 + 131072;
    const size_t OFF_MT5 = OFF_MT4 + 524288;
    const size_t OFF_XB  = OFF_MT5 + 524288;        // x_bf / x1_bf (bf16 8192x512)
    const size_t OFF_CB  = OFF_XB + 2097152;        // cat bf16 [8192,1024]
    const size_t OFF_BQ  = OFF_CB + 4194304;        // q bf16 -> x2 bf16
    const size_t OFF_BN  = OFF_BQ + 4194304;        // fold t1 scratch -> h fp32
    const size_t OFF_BC  = OFF_BN + 4194304;        // fold t2 scratch -> x1 fp32
    const size_t OFF_P   = OFF_BC + 4194304;        // fp32-converted inputs

    float* W = (float*)d_ws;
    u16* MT[6] = {(u16*)(W + OFF_MT0), (u16*)(W + OFF_MT1), (u16*)(W + OFF_MT2),
                  (u16*)(W + OFF_MT3), (u16*)(W + OFF_MT4), (u16*)(W + OFF_MT5)};
    u16*   XB  = (u16*)(W + OFF_XB);
    u16*   CB  = (u16*)(W + OFF_CB);
    u16*   QB  = (u16*)(W + OFF_BQ);   // q bf16; later x2 bf16 (sequential reuse)
    float* BN  = W + OFF_BN;           // h fp32 (after fold)
    float* BC  = W + OFF_BC;           // x1 fp32 (after fold)

    float* F[23];
    CvtBatch cb;
    int pre = 0;
    for (int i = 0; i < 23 && i < n_in; i++) {
        cb.pre4[i] = pre;
        F[i] = W + OFF_P + (size_t)pre * 4;
        cb.src[i] = d_in[i];
        cb.dst[i] = (float4*)F[i];
        pre += in_sizes[i] / 4;
    }
    cb.pre4[23] = pre;
    const int total4 = pre;
    int* FLAG = (int*)(W + OFF_P + (size_t)total4 * 4);

    if (n_in < 23) return;
    if (ws_size < (OFF_P + (size_t)total4 * 4 + 16) * sizeof(float)) return;

    detect_dtype<<<1, 256, 0, stream>>>((const u16*)d_in[0], FLAG);
    cvt_all<<<(total4 + 255) / 256, 256, 0, stream>>>(cb, total4, FLAG);
    f2b_kernel<<<(ROWS * EDIM / 4 + 255) / 256, 256, 0, stream>>>(F[0], XB, ROWS * EDIM / 4);

    // ---- fold (3 batched launches): scratch overlays BN/BC (dead here) ----
    FoldBatch fb;
    {
        const int wi[6] = {1, 4, 7, 10, 13, 16};
        u16* T1 = (u16*)BN;
        u16* T2 = (u16*)BC;
        size_t off = 0;
        for (int s = 0; s < 6; s++) {
            const int n = (s < 4) ? 512 : 1024;
            fb.w[s]  = F[wi[s]];
            fb.fw[s] = F[wi[s] + 1];
            fb.t1[s] = T1 + off;
            fb.t2[s] = T2 + off;
            fb.mt[s] = MT[s];
            fb.n[s]  = n;
            fb.lg[s] = (s < 4) ? 9 : 10;
            fb.sc[s] = (s < 4) ? 0.04419417382415922f : 0.03125f;
            off += (size_t)n * n;
        }
    }
    fold_trconv<<<dim3(32, 32, 6), 256, 0, stream>>>(fb);
    fold_circ<<<dim3(4096, 1, 6), 256, 0, stream>>>(fb);
    fold_gemm<<<dim3(8, 8, 6), 256, 0, stream>>>(fb);

    float* out0 = (float*)d_out;                       // LN(h): [8192,512]
    float* out1 = (float*)d_out + (size_t)ROWS * EDIM; // out:   [8192,1024]

    // q = x @ M0 + attn_fb                                  -> QB (bf16)
    gemm_bf<<<dim3(8, 64), 256, 0, stream>>>(
        XB, 512, MT[0], 512, F[3], nullptr, 0, QB, 512, nullptr, 0, nullptr, 0, 512, 0);
    // attention -> cat bf16 [:, :512]
    attn_mfma<<<1024, 256, 0, stream>>>(QB, CB);
    // x1 = LN(x + newx; n1)                                 -> BC fp32 + XB bf16
    ln_kernel<<<8192, 256, 0, stream>>>(F[0], 512, CB, 1024, F[19], F[20],
                                        BC, 512, XB, 512);
    // x_ln = gelu(x1 @ M1 + b); cat[:,512:]=bf16(v); x2=bf16(x1-v) -> QB
    gemm_bf<<<dim3(8, 64), 256, 0, stream>>>(
        XB, 512, MT[1], 512, F[6], nullptr, 0, CB + 512, 1024, QB, 512, BC, 512, 512, 1);
    // h = sigmoid(x2@M2+b2) * (x2@M3+b3)                     -> BN fp32
    gemm_bf2<<<dim3(8, 64), 256, 0, stream>>>(
        QB, 512, MT[2], MT[3], 512, F[9], F[12], BN, 512, 512);
    // out0 = LN(h; n2)                                       -> d_out
    ln_kernel<<<8192, 256, 0, stream>>>(BN, 512, nullptr, 0, F[21], F[22],
                                        out0, 512, nullptr, 0);
    // out1 = sigmoid(cat@M4+b4) * (cat@M5+b5)                -> d_out+4M
    gemm_bf2<<<dim3(16, 64), 256, 0, stream>>>(
        CB, 1024, MT[4], MT[5], 1024, F[15], F[18], out1, 1024, 1024);
}